// Round 7
// baseline (314.937 us; speedup 1.0000x reference)
//
#include <hip/hip_runtime.h>

#define NT 256

constexpr int Bg   = 8192;      // graphs
constexpr int NPG  = 40;
constexpr int EPG  = 640;
constexpr int IN_  = 64;
constexpr int HID  = 32;
constexpr int K1   = 20;
constexpr int K2   = 10;
constexpr int OUTC = 10;
constexpr int NE   = Bg * NPG * 16;
constexpr int SH   = 36;        // padded 32-wide row stride
constexpr float EPSF = 1e-15f;

// per-graph LDS region (floats); 2 graphs per block
constexpr int R = 6672;         // pad so graph1 base shifts 16 banks
// offsets within a graph region (all multiples of 4 for float4 alignment)
constexpr int AOFF   = 0;       // A 40x40 (A2 20x20 overlays [0,400))
constexpr int HOFF   = 1600;    // H 40xSH ; later X2 [1600,2320) + XW2r [2320,3040)
constexpr int X2OFF  = 1600;
constexpr int W2ROFF = 2320;
constexpr int XdOFF  = 3040;    // Xd 40xSH ; earlier X staging [3040,5760) stride 68
constexpr int XOFF   = 3040;
constexpr int W3ROFF = 3040;    // after Xd dead: XW3r, XW3o, X3, X4
constexpr int W3OOFF = 3400;
constexpr int X3OFF  = 3760;
constexpr int X4OFF  = 4120;
constexpr int SOFF   = 4480;    // S1 40x20 ; later S2/AS2/A3/SS2
constexpr int S2OFF  = 4480;
constexpr int AS2OFF = 4680;
constexpr int A3OFF  = 4880;
constexpr int SS2OFF = 4980;
constexpr int ASOFF  = 5280;    // AS 40x20 ; later XW2o [5280,6000)
constexpr int W2OOFF = 5280;
constexpr int SSOFF  = 6080;    // SS 20x20
constexpr int DINV   = 6480;
constexpr int ROWSA  = 6520;
constexpr int ROWM   = 6560;
constexpr int SDEN   = 6600;
constexpr int SC     = 6640;    // [0]num1 [1]den1 [2]o1 [3]den2 [8..12)f2par [12..16)tr2par

#define FMA4(acc, a, b) do { \
    float _s = (a); \
    acc.x = fmaf(_s, (b).x, acc.x); \
    acc.y = fmaf(_s, (b).y, acc.y); \
    acc.z = fmaf(_s, (b).z, acc.z); \
    acc.w = fmaf(_s, (b).w, acc.w); } while (0)

__device__ __forceinline__ float hred32(float v) {
#pragma unroll
    for (int off = 16; off > 0; off >>= 1) v += __shfl_down(v, off, 32);
    return v;
}

__device__ __forceinline__ float wave_red(float v) {
#pragma unroll
    for (int off = 32; off > 0; off >>= 1) v += __shfl_down(v, off, 64);
    return v;
}

// NOTE: launch_bounds (256,4): (256,6) caused 38KB/block scratch spill (r4).
__global__ __launch_bounds__(NT, 4)
void mincut_fused(const float* __restrict__ x, const int* __restrict__ ei,
                  const float* __restrict__ w_c1, const float* __restrict__ b_c1,
                  const float* __restrict__ w_p1, const float* __restrict__ b_p1,
                  const float* __restrict__ w2r_, const float* __restrict__ b2_,
                  const float* __restrict__ w2o_,
                  const float* __restrict__ w_p2, const float* __restrict__ b_p2,
                  const float* __restrict__ w3r_, const float* __restrict__ b3_,
                  const float* __restrict__ w3o_,
                  const float* __restrict__ w_l1, const float* __restrict__ b_l1,
                  const float* __restrict__ w_l2, const float* __restrict__ b_l2,
                  float* __restrict__ out, float* __restrict__ wsg)
{
    __shared__ __align__(16) float sm[2 * R];   // 53376 B, 2 graphs

    const int b    = blockIdx.x;     // graphs 2b, 2b+1
    const int tid  = threadIdx.x;
    const int lane = tid & 63;
    const int wid  = tid >> 6;
    const int hl   = tid & 31;
    const int hw   = tid >> 5;       // half-wave id 0..7

    // ---- iv0: edges->regs, zero A, stage X (stride 68) ----
    int aoff[5];
    {
        const int gi = tid >> 7;                 // tid<128 -> graph0 edges
        const int nb = (2 * b + gi) * NPG;
        const int base = gi * R;
        const int e0 = b * 1280 + tid * 5;
#pragma unroll
        for (int j = 0; j < 5; j++) {
            int r = ei[e0 + j] - nb, c = ei[NE + e0 + j] - nb;
            aoff[j] = base + r * NPG + c;
        }
    }
    for (int o = tid; o < 3200; o += NT) sm[(o < 1600) ? o : (R + o - 1600)] = 0.f;
    for (int o = tid; o < 1280; o += NT) {
        int gi = o >= 640; int i = o - 640 * gi;
        int n = i >> 4, k = i & 15;
        ((float4*)(sm + gi * R + XOFF + n * 68))[k] =
            ((const float4*)(x + (size_t)(2 * b + gi) * (NPG * IN_)))[i];
    }
    __syncthreads();

    // ---- iv1: adj scatter + H = X @ W1 ----
#pragma unroll
    for (int j = 0; j < 5; j++) atomicAdd(&sm[aoff[j]], 1.f);
    for (int o = tid; o < 320; o += NT) {
        int gi = o >= 160; int oo = o - 160 * gi; float* G = sm + gi * R;
        int np = oo >> 3, fq = oo & 7, n0 = 2 * np, n1 = n0 + 1;
        const float4* x0 = (const float4*)(G + XOFF + n0 * 68);
        const float4* x1 = (const float4*)(G + XOFF + n1 * 68);
        const float4* wg = (const float4*)w_c1;
        float4 acc0 = {0.f,0.f,0.f,0.f}, acc1 = {0.f,0.f,0.f,0.f};
#pragma unroll 4
        for (int kk = 0; kk < IN_ / 4; kk++) {
            float4 a0 = x0[kk], a1 = x1[kk];
            float4 w0 = wg[(4*kk+0)*8 + fq];
            float4 w1 = wg[(4*kk+1)*8 + fq];
            float4 w2 = wg[(4*kk+2)*8 + fq];
            float4 w3 = wg[(4*kk+3)*8 + fq];
            FMA4(acc0, a0.x, w0); FMA4(acc0, a0.y, w1);
            FMA4(acc0, a0.z, w2); FMA4(acc0, a0.w, w3);
            FMA4(acc1, a1.x, w0); FMA4(acc1, a1.y, w1);
            FMA4(acc1, a1.z, w2); FMA4(acc1, a1.w, w3);
        }
        ((float4*)(G + HOFF + n0 * SH))[fq] = acc0;
        ((float4*)(G + HOFF + n1 * SH))[fq] = acc1;
    }
    __syncthreads();

    // ---- iv2: degrees ----
    for (int o = tid; o < 160; o += NT) {
        int gi = o >= 80; int oo = o - 80 * gi; float* G = sm + gi * R;
        if (oo < NPG) {
            float s = 0.f;
#pragma unroll
            for (int r = 0; r < NPG; r++) s += G[r * NPG + oo];
            G[DINV + oo] = rsqrtf(s + 1.f);
        } else {
            int n = oo - NPG; float s = 0.f;
#pragma unroll
            for (int m = 0; m < NPG; m++) s += G[n * NPG + m];
            G[ROWSA + n] = s;
        }
    }
    __syncthreads();

    // ---- iv3: Xd = relu(D^-1/2 (A+I) D^-1/2 H + b1) ----
    for (int o = tid; o < 320; o += NT) {
        int gi = o >= 160; int oo = o - 160 * gi; float* G = sm + gi * R;
        int cp = oo >> 3, fq = oo & 7, c0 = 2 * cp, c1 = c0 + 1;
        float4 acc0 = {0.f,0.f,0.f,0.f}, acc1 = {0.f,0.f,0.f,0.f};
#pragma unroll 8
        for (int r = 0; r < NPG; r++) {
            float2 a2 = *(const float2*)&G[r * NPG + c0];
            float dv = G[DINV + r];
            float4 bv = ((const float4*)(G + HOFF + r * SH))[fq];
            FMA4(acc0, a2.x * dv, bv);
            FMA4(acc1, a2.y * dv, bv);
        }
        float4 bb = ((const float4*)b_c1)[fq];
        float4 h0 = ((const float4*)(G + HOFF + c0 * SH))[fq];
        float4 h1 = ((const float4*)(G + HOFF + c1 * SH))[fq];
        float d0 = G[DINV + c0], d1 = G[DINV + c1];
        float4 r0, r1;
        r0.x = fmaxf(fmaf(d0, fmaf(d0, h0.x, acc0.x), bb.x), 0.f);
        r0.y = fmaxf(fmaf(d0, fmaf(d0, h0.y, acc0.y), bb.y), 0.f);
        r0.z = fmaxf(fmaf(d0, fmaf(d0, h0.z, acc0.z), bb.z), 0.f);
        r0.w = fmaxf(fmaf(d0, fmaf(d0, h0.w, acc0.w), bb.w), 0.f);
        r1.x = fmaxf(fmaf(d1, fmaf(d1, h1.x, acc1.x), bb.x), 0.f);
        r1.y = fmaxf(fmaf(d1, fmaf(d1, h1.y, acc1.y), bb.y), 0.f);
        r1.z = fmaxf(fmaf(d1, fmaf(d1, h1.z, acc1.z), bb.z), 0.f);
        r1.w = fmaxf(fmaf(d1, fmaf(d1, h1.w, acc1.w), bb.w), 0.f);
        ((float4*)(G + XdOFF + c0 * SH))[fq] = r0;
        ((float4*)(G + XdOFF + c1 * SH))[fq] = r1;
    }
    __syncthreads();

    // ---- iv4: S1 logits ----
    for (int o = tid; o < 200; o += NT) {
        int gi = o >= 100; int oo = o - 100 * gi; float* G = sm + gi * R;
        int np = oo / 5, lq = oo - np * 5, n0 = 2 * np, n1 = n0 + 1;
        const float4* wg = (const float4*)w_p1;
        float4 bb = ((const float4*)b_p1)[lq];
        float4 acc0 = bb, acc1 = bb;
#pragma unroll 8
        for (int k = 0; k < HID; k++) {
            float a0 = G[XdOFF + n0 * SH + k];
            float a1 = G[XdOFF + n1 * SH + k];
            float4 w = wg[k * 5 + lq];
            FMA4(acc0, a0, w); FMA4(acc1, a1, w);
        }
        ((float4*)(G + SOFF + n0 * K1))[lq] = acc0;
        ((float4*)(G + SOFF + n1 * K1))[lq] = acc1;
    }
    __syncthreads();

    // ---- iv5: softmax1 ----
    if (tid < 80) {
        int gi = tid >= 40; int n = tid - 40 * gi;
        float* row = sm + gi * R + SOFF + n * K1;
        float v[K1]; float m = -3.0e38f;
#pragma unroll
        for (int k = 0; k < K1; k++) { v[k] = row[k]; m = fmaxf(m, v[k]); }
        float ssum = 0.f;
#pragma unroll
        for (int k = 0; k < K1; k++) { v[k] = __expf(v[k] - m); ssum += v[k]; }
        float inv = 1.f / ssum;
#pragma unroll
        for (int k = 0; k < K1; k++) row[k] = v[k] * inv;
    }
    __syncthreads();

    // ---- iv6: AS = A@S ; SS = S^T S ----
    for (int o = tid; o < 300; o += NT) {
        int gi = o >= 150; int oo = o - 150 * gi; float* G = sm + gi * R;
        if (oo < 100) {
            int np = oo / 5, lq = oo - np * 5, n0 = 2 * np, n1 = n0 + 1;
            const float4* sb = (const float4*)(G + SOFF);
            float4 acc0 = {0.f,0.f,0.f,0.f}, acc1 = {0.f,0.f,0.f,0.f};
#pragma unroll
            for (int m4 = 0; m4 < NPG / 4; m4++) {
                float4 a0 = *(const float4*)&G[n0 * NPG + 4 * m4];
                float4 a1 = *(const float4*)&G[n1 * NPG + 4 * m4];
                float4 b0 = sb[(4*m4+0)*5 + lq];
                float4 b1 = sb[(4*m4+1)*5 + lq];
                float4 b2v = sb[(4*m4+2)*5 + lq];
                float4 b3v = sb[(4*m4+3)*5 + lq];
                FMA4(acc0, a0.x, b0); FMA4(acc0, a0.y, b1);
                FMA4(acc0, a0.z, b2v); FMA4(acc0, a0.w, b3v);
                FMA4(acc1, a1.x, b0); FMA4(acc1, a1.y, b1);
                FMA4(acc1, a1.z, b2v); FMA4(acc1, a1.w, b3v);
            }
            ((float4*)(G + ASOFF + n0 * K1))[lq] = acc0;
            ((float4*)(G + ASOFF + n1 * K1))[lq] = acc1;
        } else {
            int m = oo - 100;
            int kp = m / 5, lq = m - kp * 5, k0 = 2 * kp, k1 = k0 + 1;
            float4 acc0 = {0.f,0.f,0.f,0.f}, acc1 = {0.f,0.f,0.f,0.f};
#pragma unroll 8
            for (int n = 0; n < NPG; n++) {
                float2 s2v = *(const float2*)&G[SOFF + n * K1 + k0];
                float4 bv = ((const float4*)(G + SOFF + n * K1))[lq];
                FMA4(acc0, s2v.x, bv); FMA4(acc1, s2v.y, bv);
            }
            ((float4*)(G + SSOFF + k0 * K1))[lq] = acc0;
            ((float4*)(G + SSOFF + k1 * K1))[lq] = acc1;
        }
    }
    __syncthreads();

    // ---- iv7: A2 = S^T AS ; X2 = S^T Xd ; den1 terms ----
    for (int o = tid; o < 340; o += NT) {
        int gi = o >= 170; int oo = o - 170 * gi; float* G = sm + gi * R;
        if (oo < 50) {
            int kp = oo / 5, lq = oo - kp * 5, k0 = 2 * kp, k1 = k0 + 1;
            float4 acc0 = {0.f,0.f,0.f,0.f}, acc1 = {0.f,0.f,0.f,0.f};
#pragma unroll 8
            for (int n = 0; n < NPG; n++) {
                float2 s2v = *(const float2*)&G[SOFF + n * K1 + k0];
                float4 bv = ((const float4*)(G + ASOFF + n * K1))[lq];
                FMA4(acc0, s2v.x, bv); FMA4(acc1, s2v.y, bv);
            }
            ((float4*)(G + AOFF + k0 * K1))[lq] = acc0;
            ((float4*)(G + AOFF + k1 * K1))[lq] = acc1;
        } else if (oo < 130) {
            int m = oo - 50;
            int kp = m >> 3, fq = m & 7, k0 = 2 * kp, k1 = k0 + 1;
            float4 acc0 = {0.f,0.f,0.f,0.f}, acc1 = {0.f,0.f,0.f,0.f};
#pragma unroll 8
            for (int n = 0; n < NPG; n++) {
                float2 s2v = *(const float2*)&G[SOFF + n * K1 + k0];
                float4 bv = ((const float4*)(G + XdOFF + n * SH))[fq];
                FMA4(acc0, s2v.x, bv); FMA4(acc1, s2v.y, bv);
            }
            ((float4*)(G + X2OFF + k0 * SH))[fq] = acc0;
            ((float4*)(G + X2OFF + k1 * SH))[fq] = acc1;
        } else {
            int n = oo - 130;
            float s2 = 0.f;
#pragma unroll
            for (int k = 0; k < K1; k++) { float v = G[SOFF + n * K1 + k]; s2 = fmaf(v, v, s2); }
            G[SDEN + n] = G[ROWSA + n] * s2;
        }
    }
    __syncthreads();

    // ---- iv8: stat slots (half-waves) + XW2r/XW2o matmuls ----
    if (hw < 2) {               // SS stats -> o1 (closed-form ortho)
        float* G = sm + hw * R;
        float f = 0.f, tr = 0.f;
        for (int i = hl; i < K1 * K1; i += 32) {
            float t = G[SSOFF + i];
            f = fmaf(t, t, f);
            if (i % (K1 + 1) == 0) tr += t;
        }
        f = hred32(f); tr = hred32(tr);
        if (hl == 0)
            G[SC + 2] = sqrtf(fmaxf(2.f - 2.f * tr / (sqrtf(f) * 4.47213595499958f), 0.f));
    } else if (hw < 4) {        // A2 stats: num1 + rownorm1
        float* G = sm + (hw - 2) * R;
        float v = 0.f;
        if (hl < K1) {
            float s = 0.f;
#pragma unroll
            for (int l = 0; l < K1; l++) s += G[AOFF + hl * K1 + l];
            float d = G[AOFF + hl * (K1 + 1)];
            G[ROWM + hl] = 1.f / (sqrtf(s - d) + EPSF);
            v = d;
        }
        v = hred32(v);
        if (hl == 0) G[SC + 0] = v;
    } else if (hw < 6) {        // den1 reduce
        float* G = sm + (hw - 4) * R;
        float v = G[SDEN + hl] + ((hl < 8) ? G[SDEN + hl + 32] : 0.f);
        v = hred32(v);
        if (hl == 0) G[SC + 1] = v;
    }
    for (int o = tid; o < 640; o += NT) {
        int gi = o >= 320; int oo = o - 320 * gi; float* G = sm + gi * R;
        int first = oo < 160; int m = first ? oo : oo - 160;
        int n = m >> 3, fq = m & 7;
        const float4* wg = (const float4*)(first ? w2r_ : w2o_);
        float4 acc = {0.f,0.f,0.f,0.f};
#pragma unroll 8
        for (int k = 0; k < HID; k++) {
            float a = G[X2OFF + n * SH + k];
            FMA4(acc, a, wg[k * 8 + fq]);
        }
        ((float4*)(G + (first ? W2ROFF : W2OOFF) + n * SH))[fq] = acc;
    }
    __syncthreads();

    // ---- ivC: X2' = relu(adj1n @ XW2r + XW2o + b2) ----
    for (int o = tid; o < 160; o += NT) {
        int gi = o >= 80; int oo = o - 80 * gi; float* G = sm + gi * R;
        int kp = oo >> 3, fq = oo & 7, k0 = 2 * kp, k1 = k0 + 1;
        float4 acc0 = {0.f,0.f,0.f,0.f}, acc1 = {0.f,0.f,0.f,0.f};
#pragma unroll
        for (int l = 0; l < K1; l++) {
            float rl = G[ROWM + l];
            float a0 = (l == k0) ? 0.f : G[AOFF + k0 * K1 + l];
            float a1 = (l == k1) ? 0.f : G[AOFF + k1 * K1 + l];
            float4 w = ((const float4*)(G + W2ROFF + l * SH))[fq];
            FMA4(acc0, a0 * rl, w); FMA4(acc1, a1 * rl, w);
        }
        float4 bb = ((const float4*)b2_)[fq];
        float4 o0 = ((const float4*)(G + W2OOFF + k0 * SH))[fq];
        float4 o1 = ((const float4*)(G + W2OOFF + k1 * SH))[fq];
        float rk0 = G[ROWM + k0], rk1 = G[ROWM + k1];
        float4 r0, r1;
        r0.x = fmaxf(fmaf(rk0, acc0.x, o0.x + bb.x), 0.f);
        r0.y = fmaxf(fmaf(rk0, acc0.y, o0.y + bb.y), 0.f);
        r0.z = fmaxf(fmaf(rk0, acc0.z, o0.z + bb.z), 0.f);
        r0.w = fmaxf(fmaf(rk0, acc0.w, o0.w + bb.w), 0.f);
        r1.x = fmaxf(fmaf(rk1, acc1.x, o1.x + bb.x), 0.f);
        r1.y = fmaxf(fmaf(rk1, acc1.y, o1.y + bb.y), 0.f);
        r1.z = fmaxf(fmaf(rk1, acc1.z, o1.z + bb.z), 0.f);
        r1.w = fmaxf(fmaf(rk1, acc1.w, o1.w + bb.w), 0.f);
        ((float4*)(G + X2OFF + k0 * SH))[fq] = r0;
        ((float4*)(G + X2OFF + k1 * SH))[fq] = r1;
    }
    __syncthreads();

    // ---- ivD: S2 logits ----
    for (int o = tid; o < 400; o += NT) {
        int gi = o >= 200; int oo = o - 200 * gi; float* G = sm + gi * R;
        int n = oo / K2, q = oo - n * K2;
        float acc = b_p2[q];
#pragma unroll 8
        for (int j = 0; j < HID; j++) acc = fmaf(G[X2OFF + n * SH + j], w_p2[j * K2 + q], acc);
        G[S2OFF + oo] = acc;
    }
    __syncthreads();

    // ---- ivE: softmax2 ----
    if (tid < 40) {
        int gi = tid >= 20; int n = tid - 20 * gi;
        float* row = sm + gi * R + S2OFF + n * K2;
        float v[K2]; float m = -3.0e38f;
#pragma unroll
        for (int q = 0; q < K2; q++) { v[q] = row[q]; m = fmaxf(m, v[q]); }
        float ssum = 0.f;
#pragma unroll
        for (int q = 0; q < K2; q++) { v[q] = __expf(v[q] - m); ssum += v[q]; }
        float inv = 1.f / ssum;
#pragma unroll
        for (int q = 0; q < K2; q++) row[q] = v[q] * inv;
    }
    __syncthreads();

    // ---- ivF: AS2 ; SS2 ; X3 = S2^T X2' ; den2 terms ----
    for (int o = tid; o < 840; o += NT) {
        int gi = o >= 420; int oo = o - 420 * gi; float* G = sm + gi * R;
        if (oo < 200) {
            int n = oo / K2, l = oo - n * K2;
            float acc = 0.f;
#pragma unroll
            for (int m = 0; m < K1; m++) {
                float a = (m == n) ? 0.f : G[AOFF + n * K1 + m];
                acc = fmaf(a * G[ROWM + m], G[S2OFF + m * K2 + l], acc);
            }
            G[AS2OFF + oo] = acc * G[ROWM + n];
        } else if (oo < 300) {
            int m = oo - 200; int k = m / K2, l = m - k * K2;
            float acc = 0.f;
#pragma unroll
            for (int n = 0; n < K1; n++) acc = fmaf(G[S2OFF + n * K2 + k], G[S2OFF + n * K2 + l], acc);
            G[SS2OFF + m] = acc;
        } else if (oo < 380) {
            int m = oo - 300; int k = m >> 3, fq = m & 7;
            float4 acc = {0.f,0.f,0.f,0.f};
#pragma unroll
            for (int n = 0; n < K1; n++) {
                float a = G[S2OFF + n * K2 + k];
                float4 bv = ((const float4*)(G + X2OFF + n * SH))[fq];
                FMA4(acc, a, bv);
            }
            ((float4*)(G + X3OFF + k * SH))[fq] = acc;
        } else {
            int n = oo - 380;
            float da = 0.f, s2 = 0.f;
#pragma unroll
            for (int l = 0; l < K1; l++) {
                float a = (l == n) ? 0.f : G[AOFF + n * K1 + l];
                da = fmaf(a, G[ROWM + l], da);
            }
            da *= G[ROWM + n];
#pragma unroll
            for (int q = 0; q < K2; q++) { float v = G[S2OFF + n * K2 + q]; s2 = fmaf(v, v, s2); }
            G[SDEN + n] = da * s2;
        }
    }
    __syncthreads();

    // ---- ivG: A3 = S2^T AS2 ; den2 ; SS2-stat partials ----
    if (tid < 200) {
        int gi = tid >= 100; int oo = tid - 100 * gi; float* G = sm + gi * R;
        int k = oo / K2, l = oo - k * K2;
        float acc = 0.f;
#pragma unroll
        for (int n = 0; n < K1; n++) acc = fmaf(G[S2OFF + n * K2 + k], G[AS2OFF + n * K2 + l], acc);
        G[A3OFF + oo] = acc;
    } else if (tid == 200 || tid == 201) {
        float* G = sm + (tid - 200) * R;
        float s = 0.f;
#pragma unroll
        for (int l = 0; l < K1; l++) s += G[SDEN + l];
        G[SC + 3] = s;
    } else if (tid >= 204 && tid < 212) {
        int j = tid - 204; float* G = sm + (j >> 2) * R; int t = j & 3;
        float f = 0.f, tr = 0.f;
        for (int i = 25 * t; i < 25 * t + 25; i++) {
            float v = G[SS2OFF + i];
            f = fmaf(v, v, f);
            if (i % (K2 + 1) == 0) tr += v;
        }
        G[SC + 8 + t] = f; G[SC + 12 + t] = tr;
    }
    __syncthreads();

    // ---- ivH: rownorm2 + per-graph loss ----
    if (tid < 10 || (tid >= 32 && tid < 42)) {
        int gi = tid >= 32; int l = tid - 32 * gi; float* G = sm + gi * R;
        float s = 0.f;
#pragma unroll
        for (int m = 0; m < K2; m++) s += G[A3OFF + l * K2 + m];
        s -= G[A3OFF + l * (K2 + 1)];
        G[ROWM + l] = 1.f / (sqrtf(s) + EPSF);
    } else if (tid == 64 || tid == 65) {
        int gi = tid - 64; float* G = sm + gi * R;
        float f  = G[SC+8] + G[SC+9] + G[SC+10] + G[SC+11];
        float tr = G[SC+12] + G[SC+13] + G[SC+14] + G[SC+15];
        float o2 = sqrtf(fmaxf(2.f - 2.f * tr / (sqrtf(f) * 3.1622776601683795f), 0.f));
        float num2 = 0.f;
#pragma unroll
        for (int k = 0; k < K2; k++) num2 += G[A3OFF + k * (K2 + 1)];
        float loss = -(G[SC+0] / G[SC+1]) + G[SC+2] - num2 / G[SC+3] + o2;
        wsg[2 * b + gi] = loss;
    }
    __syncthreads();

    // ---- ivI: XW3r = X3@w3r ; XW3o = X3@w3o ----
    for (int o = tid; o < 320; o += NT) {
        int gi = o >= 160; int oo = o - 160 * gi; float* G = sm + gi * R;
        int first = oo < 80; int m = first ? oo : oo - 80;
        int n = m >> 3, fq = m & 7;
        const float4* wg = (const float4*)(first ? w3r_ : w3o_);
        float4 acc = {0.f,0.f,0.f,0.f};
#pragma unroll 8
        for (int k = 0; k < HID; k++) {
            float a = G[X3OFF + n * SH + k];
            FMA4(acc, a, wg[k * 8 + fq]);
        }
        ((float4*)(G + (first ? W3ROFF : W3OOFF) + n * SH))[fq] = acc;
    }
    __syncthreads();

    // ---- ivJ: X4 = adj2n @ XW3r + XW3o + b3 ----
    if (tid < 80) {
        int gi = tid >= 40; int oo = tid - 40 * gi; float* G = sm + gi * R;
        int kp = oo >> 3, fq = oo & 7, k0 = 2 * kp, k1 = k0 + 1;
        float4 acc0 = {0.f,0.f,0.f,0.f}, acc1 = {0.f,0.f,0.f,0.f};
#pragma unroll
        for (int l = 0; l < K2; l++) {
            float rl = G[ROWM + l];
            float a0 = (l == k0) ? 0.f : G[A3OFF + k0 * K2 + l];
            float a1 = (l == k1) ? 0.f : G[A3OFF + k1 * K2 + l];
            float4 w = ((const float4*)(G + W3ROFF + l * SH))[fq];
            FMA4(acc0, a0 * rl, w); FMA4(acc1, a1 * rl, w);
        }
        float4 bb = ((const float4*)b3_)[fq];
        float4 o0 = ((const float4*)(G + W3OOFF + k0 * SH))[fq];
        float4 o1 = ((const float4*)(G + W3OOFF + k1 * SH))[fq];
        float rk0 = G[ROWM + k0], rk1 = G[ROWM + k1];
        float4 r0, r1;
        r0.x = fmaf(rk0, acc0.x, o0.x + bb.x);
        r0.y = fmaf(rk0, acc0.y, o0.y + bb.y);
        r0.z = fmaf(rk0, acc0.z, o0.z + bb.z);
        r0.w = fmaf(rk0, acc0.w, o0.w + bb.w);
        r1.x = fmaf(rk1, acc1.x, o1.x + bb.x);
        r1.y = fmaf(rk1, acc1.y, o1.y + bb.y);
        r1.z = fmaf(rk1, acc1.z, o1.z + bb.z);
        r1.w = fmaf(rk1, acc1.w, o1.w + bb.w);
        ((float4*)(G + X4OFF + k0 * SH))[fq] = r0;
        ((float4*)(G + X4OFF + k1 * SH))[fq] = r1;
    }
    __syncthreads();

    // ---- ivK: mean pool + MLP head (one wave per graph) ----
    if (wid < 2) {
        int gi = wid; float* G = sm + gi * R;
        int f = lane & 31;
        float pool = 0.f;
#pragma unroll
        for (int n = 0; n < K2; n++) pool += G[X4OFF + n * SH + f];
        pool *= (1.f / K2);
        float acc = b_l1[f];
#pragma unroll
        for (int j = 0; j < HID; j++)
            acc = fmaf(__shfl(pool, j, 64), w_l1[j * HID + f], acc);
        float t1 = fmaxf(acc, 0.f);
        int o = (lane < OUTC) ? lane : 0;
        float acc2 = b_l2[o];
#pragma unroll
        for (int j = 0; j < HID; j++)
            acc2 = fmaf(__shfl(t1, j, 64), w_l2[j * OUTC + o], acc2);
        if (lane < OUTC) out[(size_t)(2 * b + gi) * OUTC + lane] = acc2;
    }
}

__global__ void loss_reduce(const float* __restrict__ wsg, float* __restrict__ out)
{
    __shared__ float sred[4];
    int tid = threadIdx.x;
    float s = 0.f;
    for (int i = tid; i < Bg; i += NT) s += wsg[i];
    s = wave_red(s);
    if ((tid & 63) == 0) sred[tid >> 6] = s;
    __syncthreads();
    if (tid == 0) out[(size_t)Bg * OUTC] = (sred[0] + sred[1] + sred[2] + sred[3]) * (1.f / Bg);
}

extern "C" void kernel_launch(void* const* d_in, const int* in_sizes, int n_in,
                              void* d_out, int out_size, void* d_ws, size_t ws_size,
                              hipStream_t stream)
{
    const float* x    = (const float*)d_in[0];
    const int*   ei   = (const int*)  d_in[1];
    // d_in[2] = batch (unused: graphs are contiguous blocks of NPG nodes)
    const float* w_c1 = (const float*)d_in[3];
    const float* b_c1 = (const float*)d_in[4];
    const float* w_p1 = (const float*)d_in[5];
    const float* b_p1 = (const float*)d_in[6];
    const float* w2r  = (const float*)d_in[7];
    const float* b2   = (const float*)d_in[8];
    const float* w2o  = (const float*)d_in[9];
    const float* w_p2 = (const float*)d_in[10];
    const float* b_p2 = (const float*)d_in[11];
    const float* w3r  = (const float*)d_in[12];
    const float* b3   = (const float*)d_in[13];
    const float* w3o  = (const float*)d_in[14];
    const float* w_l1 = (const float*)d_in[15];
    const float* b_l1 = (const float*)d_in[16];
    const float* w_l2 = (const float*)d_in[17];
    const float* b_l2 = (const float*)d_in[18];
    float* out = (float*)d_out;
    float* wsg = (float*)d_ws;

    hipLaunchKernelGGL(mincut_fused, dim3(Bg / 2), dim3(NT), 0, stream,
                       x, ei, w_c1, b_c1, w_p1, b_p1, w2r, b2, w2o,
                       w_p2, b_p2, w3r, b3, w3o, w_l1, b_l1, w_l2, b_l2,
                       out, wsg);
    hipLaunchKernelGGL(loss_reduce, dim3(1), dim3(NT), 0, stream, wsg, out);
}

// Round 8
// 258.277 us; speedup vs baseline: 1.2194x; 1.2194x over previous
//
#include <hip/hip_runtime.h>

#define NT 256

constexpr int Bg   = 8192;      // graphs
constexpr int NPG  = 40;
constexpr int EPG  = 640;
constexpr int IN_  = 64;
constexpr int HID  = 32;
constexpr int K1   = 20;
constexpr int K2   = 10;
constexpr int OUTC = 10;
constexpr int NE   = Bg * NPG * 16;
constexpr int SX   = 68;        // padded X row stride
constexpr int SH   = 36;        // padded 32-wide row stride
constexpr float EPSF = 1e-15f;

#define FMA4(acc, a, b) do { \
    float _s = (a); \
    acc.x = fmaf(_s, (b).x, acc.x); \
    acc.y = fmaf(_s, (b).y, acc.y); \
    acc.z = fmaf(_s, (b).z, acc.z); \
    acc.w = fmaf(_s, (b).w, acc.w); } while (0)

__device__ __forceinline__ float wave_red(float v) {
#pragma unroll
    for (int off = 32; off > 0; off >>= 1) v += __shfl_down(v, off, 64);
    return v;
}

// LDS overlay (floats):
//  sA   [1600]: raw A (p0-p6); A2 = S^T A S raw overlays [0,400) from p7 (kept raw;
//               row-norm factors folded at every consumer, diag skipped there)
//  sXbuf[2720]: X staging stride 68 (p0-p1); then S1@0(800) AS/AX@800(800) SS/SS2@1600(400)
//  sH   [1440]: H (p1-p3); then X2@0(720) S2@720(200) X3@920(360) A3@1280(100); X4@0 (p15)
//  sXd  [1440]: Xd (p3-p7); then Xw2o (p8-p10); then XW3r@0(360) XW3o@360(360) (p14+)
// NOTE: __launch_bounds__(256,4) — (256,6) forced 40 VGPR + 38KB/block scratch spill (r4).
// LDS 30.3KB -> 5 blocks/CU (r3's 36.9KB gave 4).
__global__ __launch_bounds__(NT, 4)
void mincut_fused(const float* __restrict__ x, const int* __restrict__ ei,
                  const float* __restrict__ w_c1, const float* __restrict__ b_c1,
                  const float* __restrict__ w_p1, const float* __restrict__ b_p1,
                  const float* __restrict__ w2r_, const float* __restrict__ b2_,
                  const float* __restrict__ w2o_,
                  const float* __restrict__ w_p2, const float* __restrict__ b_p2,
                  const float* __restrict__ w3r_, const float* __restrict__ b3_,
                  const float* __restrict__ w3o_,
                  const float* __restrict__ w_l1, const float* __restrict__ b_l1,
                  const float* __restrict__ w_l2, const float* __restrict__ b_l2,
                  float* __restrict__ out, float* __restrict__ wsg)
{
    __shared__ __align__(16) float sA[NPG * NPG];    // 1600
    __shared__ __align__(16) float sXbuf[NPG * SX];  // 2720
    __shared__ __align__(16) float sH[NPG * SH];     // 1440
    __shared__ __align__(16) float sXd[NPG * SH];    // 1440
    __shared__ __align__(16) float sdinv[NPG];
    __shared__ __align__(16) float srowsA[NPG];
    __shared__ __align__(16) float srowm[NPG];
    __shared__ __align__(16) float sden[NPG];
    __shared__ __align__(16) float sc[8];
    // sc: [0]num1 [1]den1 [2]o1 [5]den2 [6]o2

    float* sA2  = sA;            // 20x20 raw (p7+)
    float* sS   = sXbuf;         // 40x20
    float* sAS  = sXbuf + 800;   // AS (p6-p7), AX (p9-p10), AS2 (p12-p13)
    float* sSS  = sXbuf + 1600;  // SS (p6-p8), SS2 (p12-p13)
    float* sX2  = sH;            // 20xSH (p7+); X4 reuses @0 (p15)
    float* sS2  = sH + 720;      // 20x10
    float* sX3  = sH + 920;      // 10xSH
    float* sA3  = sH + 1280;     // 10x10 raw
    float* sXw2o= sXd;           // 20xSH (p8-p10)
    float* sW3r = sXd;           // 10xSH (p14+)
    float* sW3o = sXd + 360;     // 10xSH
    float* sX4  = sH;            // 10xSH (p15)

    const int g    = blockIdx.x;
    const int tid  = threadIdx.x;
    const int lane = tid & 63;
    const int wid  = tid >> 6;

    // ---- p0: edges -> regs, zero A, stage X ----
    int er0, ec0, er1, ec1, er2 = -1, ec2 = 0;
    {
        const int eb = g * EPG, nb = g * NPG;
        int e = eb + tid;
        er0 = ei[e] - nb; ec0 = ei[NE + e] - nb;
        e += NT;
        er1 = ei[e] - nb; ec1 = ei[NE + e] - nb;
        if (tid + 2 * NT < EPG) {
            e += NT;
            er2 = ei[e] - nb; ec2 = ei[NE + e] - nb;
        }
    }
    for (int i = tid; i < NPG * NPG; i += NT) sA[i] = 0.f;
    {
        const float4* xg = (const float4*)(x + (size_t)g * (NPG * IN_));
        for (int i = tid; i < NPG * (IN_ / 4); i += NT) {
            int n = i >> 4, k = i & 15;
            ((float4*)(sXbuf + n * SX))[k] = xg[i];
        }
    }
    __syncthreads();

    // ---- p1: adj scatter + H = X @ W1 (2-row tiles) ----
    atomicAdd(&sA[er0 * NPG + ec0], 1.f);
    atomicAdd(&sA[er1 * NPG + ec1], 1.f);
    if (er2 >= 0) atomicAdd(&sA[er2 * NPG + ec2], 1.f);

    if (tid < 160) {
        int np = tid >> 3, fq = tid & 7;
        int n0 = 2 * np, n1 = n0 + 1;
        const float4* a0p = (const float4*)(sXbuf + n0 * SX);
        const float4* a1p = (const float4*)(sXbuf + n1 * SX);
        const float4* wg  = (const float4*)w_c1;
        float4 acc0 = {0.f,0.f,0.f,0.f}, acc1 = {0.f,0.f,0.f,0.f};
#pragma unroll 4
        for (int kk = 0; kk < IN_ / 4; kk++) {
            float4 a0 = a0p[kk], a1 = a1p[kk];
            float4 w0 = wg[(4*kk+0)*8 + fq];
            float4 w1 = wg[(4*kk+1)*8 + fq];
            float4 w2 = wg[(4*kk+2)*8 + fq];
            float4 w3 = wg[(4*kk+3)*8 + fq];
            FMA4(acc0, a0.x, w0); FMA4(acc0, a0.y, w1);
            FMA4(acc0, a0.z, w2); FMA4(acc0, a0.w, w3);
            FMA4(acc1, a1.x, w0); FMA4(acc1, a1.y, w1);
            FMA4(acc1, a1.z, w2); FMA4(acc1, a1.w, w3);
        }
        ((float4*)(sH + n0 * SH))[fq] = acc0;
        ((float4*)(sH + n1 * SH))[fq] = acc1;
    }
    __syncthreads();

    // ---- p2: degrees ----
    if (tid < NPG) {
        float s = 0.f;
#pragma unroll
        for (int r = 0; r < NPG; r++) s += sA[r * NPG + tid];
        sdinv[tid] = rsqrtf(s + 1.f);
    } else if (tid >= 64 && tid < 64 + NPG) {
        int n = tid - 64; float s = 0.f;
#pragma unroll
        for (int m = 0; m < NPG; m++) s += sA[n * NPG + m];
        srowsA[n] = s;
    }
    __syncthreads();

    // ---- p3: Xd = relu(D^-1/2 (A+I) D^-1/2 H + b1)  [dinv folded] ----
    if (tid < 160) {
        int cp = tid >> 3, fq = tid & 7;
        int c0 = 2 * cp, c1 = c0 + 1;
        float4 acc0 = {0.f,0.f,0.f,0.f}, acc1 = {0.f,0.f,0.f,0.f};
#pragma unroll 8
        for (int r = 0; r < NPG; r++) {
            float2 a2 = *(const float2*)&sA[r * NPG + c0];
            float dv = sdinv[r];
            float4 bv = ((const float4*)(sH + r * SH))[fq];
            FMA4(acc0, a2.x * dv, bv);
            FMA4(acc1, a2.y * dv, bv);
        }
        float4 bb = ((const float4*)b_c1)[fq];
        float4 h0 = ((const float4*)(sH + c0 * SH))[fq];
        float4 h1 = ((const float4*)(sH + c1 * SH))[fq];
        float d0 = sdinv[c0], d1 = sdinv[c1];
        float4 r0, r1;
        r0.x = fmaxf(fmaf(d0, fmaf(d0, h0.x, acc0.x), bb.x), 0.f);
        r0.y = fmaxf(fmaf(d0, fmaf(d0, h0.y, acc0.y), bb.y), 0.f);
        r0.z = fmaxf(fmaf(d0, fmaf(d0, h0.z, acc0.z), bb.z), 0.f);
        r0.w = fmaxf(fmaf(d0, fmaf(d0, h0.w, acc0.w), bb.w), 0.f);
        r1.x = fmaxf(fmaf(d1, fmaf(d1, h1.x, acc1.x), bb.x), 0.f);
        r1.y = fmaxf(fmaf(d1, fmaf(d1, h1.y, acc1.y), bb.y), 0.f);
        r1.z = fmaxf(fmaf(d1, fmaf(d1, h1.z, acc1.z), bb.z), 0.f);
        r1.w = fmaxf(fmaf(d1, fmaf(d1, h1.w, acc1.w), bb.w), 0.f);
        ((float4*)(sXd + c0 * SH))[fq] = r0;
        ((float4*)(sXd + c1 * SH))[fq] = r1;
    }
    __syncthreads();

    // ---- p4: S1 logits = Xd @ Wp1 + bp1 ----
    if (tid < 100) {
        int np = tid / 5, lq = tid - np * 5;
        int n0 = 2 * np, n1 = n0 + 1;
        const float4* wg = (const float4*)w_p1;
        float4 bb = ((const float4*)b_p1)[lq];
        float4 acc0 = bb, acc1 = bb;
#pragma unroll 8
        for (int k = 0; k < HID; k++) {
            float a0 = sXd[n0 * SH + k];
            float a1 = sXd[n1 * SH + k];
            float4 w = wg[k * 5 + lq];
            FMA4(acc0, a0, w); FMA4(acc1, a1, w);
        }
        ((float4*)(sS + n0 * K1))[lq] = acc0;
        ((float4*)(sS + n1 * K1))[lq] = acc1;
    }
    __syncthreads();

    // ---- p5: softmax1 ----
    if (tid < NPG) {
        float* row = sS + tid * K1;
        float v[K1]; float m = -3.0e38f;
#pragma unroll
        for (int k = 0; k < K1; k++) { v[k] = row[k]; m = fmaxf(m, v[k]); }
        float ssum = 0.f;
#pragma unroll
        for (int k = 0; k < K1; k++) { v[k] = __expf(v[k] - m); ssum += v[k]; }
        float inv = 1.f / ssum;
#pragma unroll
        for (int k = 0; k < K1; k++) row[k] = v[k] * inv;
    }
    __syncthreads();

    // ---- p6: AS = A @ S ; SS = S^T S ----
    if (tid < 100) {
        int np = tid / 5, lq = tid - np * 5;
        int n0 = 2 * np, n1 = n0 + 1;
        const float4* sb = (const float4*)sS;
        float4 acc0 = {0.f,0.f,0.f,0.f}, acc1 = {0.f,0.f,0.f,0.f};
#pragma unroll
        for (int m4 = 0; m4 < NPG / 4; m4++) {
            float4 a0 = *(const float4*)&sA[n0 * NPG + 4 * m4];
            float4 a1 = *(const float4*)&sA[n1 * NPG + 4 * m4];
            float4 b0 = sb[(4*m4+0)*5 + lq];
            float4 b1 = sb[(4*m4+1)*5 + lq];
            float4 b2v = sb[(4*m4+2)*5 + lq];
            float4 b3v = sb[(4*m4+3)*5 + lq];
            FMA4(acc0, a0.x, b0); FMA4(acc0, a0.y, b1);
            FMA4(acc0, a0.z, b2v); FMA4(acc0, a0.w, b3v);
            FMA4(acc1, a1.x, b0); FMA4(acc1, a1.y, b1);
            FMA4(acc1, a1.z, b2v); FMA4(acc1, a1.w, b3v);
        }
        ((float4*)(sAS + n0 * K1))[lq] = acc0;
        ((float4*)(sAS + n1 * K1))[lq] = acc1;
    } else if (tid < 150) {
        int oo = tid - 100;
        int kp = oo / 5, lq = oo - kp * 5;
        int k0 = 2 * kp, k1 = k0 + 1;
        float4 acc0 = {0.f,0.f,0.f,0.f}, acc1 = {0.f,0.f,0.f,0.f};
#pragma unroll 8
        for (int n = 0; n < NPG; n++) {
            float2 s2v = *(const float2*)&sS[n * K1 + k0];
            float4 bv = ((const float4*)(sS + n * K1))[lq];
            FMA4(acc0, s2v.x, bv); FMA4(acc1, s2v.y, bv);
        }
        ((float4*)(sSS + k0 * K1))[lq] = acc0;
        ((float4*)(sSS + k1 * K1))[lq] = acc1;
    }
    __syncthreads();

    // ---- p7: A2 = S^T AS (raw) ; X2 = S^T Xd ; den1 terms ----
    if (tid < 50) {
        int kp = tid / 5, lq = tid - kp * 5;
        int k0 = 2 * kp, k1 = k0 + 1;
        float4 acc0 = {0.f,0.f,0.f,0.f}, acc1 = {0.f,0.f,0.f,0.f};
#pragma unroll 8
        for (int n = 0; n < NPG; n++) {
            float2 s2v = *(const float2*)&sS[n * K1 + k0];
            float4 bv = ((const float4*)(sAS + n * K1))[lq];
            FMA4(acc0, s2v.x, bv); FMA4(acc1, s2v.y, bv);
        }
        ((float4*)(sA2 + k0 * K1))[lq] = acc0;
        ((float4*)(sA2 + k1 * K1))[lq] = acc1;
    } else if (tid < 130) {
        int oo = tid - 50;
        int kp = oo >> 3, fq = oo & 7;
        int k0 = 2 * kp, k1 = k0 + 1;
        float4 acc0 = {0.f,0.f,0.f,0.f}, acc1 = {0.f,0.f,0.f,0.f};
#pragma unroll 8
        for (int n = 0; n < NPG; n++) {
            float2 s2v = *(const float2*)&sS[n * K1 + k0];
            float4 bv = ((const float4*)(sXd + n * SH))[fq];
            FMA4(acc0, s2v.x, bv); FMA4(acc1, s2v.y, bv);
        }
        ((float4*)(sX2 + k0 * SH))[fq] = acc0;
        ((float4*)(sX2 + k1 * SH))[fq] = acc1;
    } else if (tid < 170) {
        int n = tid - 130;
        float s2 = 0.f;
#pragma unroll
        for (int k = 0; k < K1; k++) { float v = sS[n * K1 + k]; s2 = fmaf(v, v, s2); }
        sden[n] = srowsA[n] * s2;
    }
    __syncthreads();

    // ---- p8: stats (3 waves) + Xw2o = X2 @ w2o ----
    if (wid == 0) {              // closed-form ortho1 from SS
        float f = 0.f, tr = 0.f;
        for (int i = lane; i < K1 * K1; i += 64) {
            float t = sSS[i];
            f = fmaf(t, t, f);
            if (i % (K1 + 1) == 0) tr += t;
        }
        f = wave_red(f); tr = wave_red(tr);
        if (lane == 0)
            sc[2] = sqrtf(fmaxf(2.f - 2.f * tr / (sqrtf(f) * 4.47213595499958f), 0.f));
    } else if (wid == 1) {       // num1 = trace(A2) ; rownorm1 (A2 kept raw)
        float v = 0.f;
        if (lane < K1) {
            float s = 0.f;
#pragma unroll
            for (int l = 0; l < K1; l++) s += sA2[lane * K1 + l];
            float d = sA2[lane * (K1 + 1)];
            srowm[lane] = 1.f / (sqrtf(s - d) + EPSF);
            v = d;
        }
        v = wave_red(v);
        if (lane == 0) sc[0] = v;
    } else if (wid == 2) {       // den1
        float v = (lane < NPG) ? sden[lane] : 0.f;
        v = wave_red(v);
        if (lane == 0) sc[1] = v;
    }
    if (tid < 160) {             // Xw2o (1-row x 8fq)
        int n = tid >> 3, fq = tid & 7;
        const float4* wg = (const float4*)w2o_;
        float4 acc = {0.f,0.f,0.f,0.f};
#pragma unroll 8
        for (int k = 0; k < HID; k++) {
            float a = sX2[n * SH + k];
            FMA4(acc, a, wg[k * 8 + fq]);
        }
        ((float4*)(sXw2o + n * SH))[fq] = acc;
    }
    __syncthreads();

    // ---- p9: AX = adj1n @ X2  [norm folded, diag skipped] ----
    if (tid < 160) {
        int k = tid >> 3, fq = tid & 7;
        float4 acc = {0.f,0.f,0.f,0.f};
#pragma unroll
        for (int l = 0; l < K1; l++) {
            float a = (l == k) ? 0.f : sA2[k * K1 + l];
            float4 bv = ((const float4*)(sX2 + l * SH))[fq];
            FMA4(acc, a * srowm[l], bv);
        }
        float rk = srowm[k];
        acc.x *= rk; acc.y *= rk; acc.z *= rk; acc.w *= rk;
        ((float4*)(sAS + k * SH))[fq] = acc;
    }
    __syncthreads();

    // ---- p10: X2' = relu(AX @ W2r + b2 + Xw2o) ----
    if (tid < 160) {
        int k = tid >> 3, fq = tid & 7;
        const float4* wg = (const float4*)w2r_;
        float4 bb = ((const float4*)b2_)[fq];
        float4 oo = ((const float4*)(sXw2o + k * SH))[fq];
        float4 acc;
        acc.x = bb.x + oo.x; acc.y = bb.y + oo.y;
        acc.z = bb.z + oo.z; acc.w = bb.w + oo.w;
#pragma unroll 8
        for (int j = 0; j < HID; j++) {
            float a = sAS[k * SH + j];
            FMA4(acc, a, wg[j * 8 + fq]);
        }
        acc.x = fmaxf(acc.x, 0.f); acc.y = fmaxf(acc.y, 0.f);
        acc.z = fmaxf(acc.z, 0.f); acc.w = fmaxf(acc.w, 0.f);
        ((float4*)(sX2 + k * SH))[fq] = acc;
    }
    __syncthreads();

    // ---- p11a: S2 logits ----
    if (tid < K1 * K2) {
        int n = tid / K2, q = tid - n * K2;
        float acc = b_p2[q];
#pragma unroll 8
        for (int j = 0; j < HID; j++) acc = fmaf(sX2[n * SH + j], w_p2[j * K2 + q], acc);
        sS2[tid] = acc;
    }
    __syncthreads();

    // ---- p11b: softmax2 ----
    if (tid < K1) {
        float* row = sS2 + tid * K2;
        float v[K2]; float m = -3.0e38f;
#pragma unroll
        for (int q = 0; q < K2; q++) { v[q] = row[q]; m = fmaxf(m, v[q]); }
        float ssum = 0.f;
#pragma unroll
        for (int q = 0; q < K2; q++) { v[q] = __expf(v[q] - m); ssum += v[q]; }
        float inv = 1.f / ssum;
#pragma unroll
        for (int q = 0; q < K2; q++) row[q] = v[q] * inv;
    }
    __syncthreads();

    // ---- p12: AS2 = adj1n@S2 ; SS2 ; X3 = S2^T X2' ; den2 terms ----
    for (int o = tid; o < 400; o += NT) {
        if (o < 200) {
            int n = o / K2, l = o - n * K2;
            float acc = 0.f;
#pragma unroll
            for (int m = 0; m < K1; m++) {
                float a = (m == n) ? 0.f : sA2[n * K1 + m];
                acc = fmaf(a * srowm[m], sS2[m * K2 + l], acc);
            }
            sAS[n * K2 + l] = acc * srowm[n];
        } else if (o < 300) {
            int oo = o - 200; int k = oo / K2, l = oo - k * K2;
            float acc = 0.f;
#pragma unroll
            for (int n = 0; n < K1; n++) acc = fmaf(sS2[n * K2 + k], sS2[n * K2 + l], acc);
            sSS[oo] = acc;
        } else if (o < 380) {
            int oo = o - 300; int k = oo >> 3, fq = oo & 7;
            float4 acc = {0.f,0.f,0.f,0.f};
#pragma unroll
            for (int n = 0; n < K1; n++) {
                float a = sS2[n * K2 + k];
                float4 bv = ((const float4*)(sX2 + n * SH))[fq];
                FMA4(acc, a, bv);
            }
            ((float4*)(sX3 + k * SH))[fq] = acc;
        } else {
            int n = o - 380;
            float da = 0.f, s2 = 0.f;
#pragma unroll
            for (int l = 0; l < K1; l++) {
                float a = (l == n) ? 0.f : sA2[n * K1 + l];
                da = fmaf(a, srowm[l], da);
            }
            da *= srowm[n];
#pragma unroll
            for (int q = 0; q < K2; q++) { float v = sS2[n * K2 + q]; s2 = fmaf(v, v, s2); }
            sden[n] = da * s2;
        }
    }
    __syncthreads();

    // ---- p13: A3 = S2^T AS2 (raw) ; den2 reduce ; ortho2 closed-form ----
    if (tid < K2 * K2) {
        int k = tid / K2, l = tid - k * K2;
        float acc = 0.f;
#pragma unroll
        for (int n = 0; n < K1; n++) acc = fmaf(sS2[n * K2 + k], sAS[n * K2 + l], acc);
        sA3[tid] = acc;
    } else if (wid == 2) {
        float v = (lane < K1) ? sden[lane] : 0.f;
        v = wave_red(v);
        if (lane == 0) sc[5] = v;
    } else if (wid == 3) {
        float f = 0.f, tr = 0.f;
        for (int i = lane; i < K2 * K2; i += 64) {
            float t = sSS[i];
            f = fmaf(t, t, f);
            if (i % (K2 + 1) == 0) tr += t;
        }
        f = wave_red(f); tr = wave_red(tr);
        if (lane == 0)
            sc[6] = sqrtf(fmaxf(2.f - 2.f * tr / (sqrtf(f) * 3.1622776601683795f), 0.f));
    }
    __syncthreads();

    // ---- p14: XW3r/XW3o ; rownorm2 ; loss write ----
    if (tid < 160) {
        bool first = (tid < 80);
        int oo = first ? tid : tid - 80;
        int n = oo >> 3, fq = oo & 7;
        const float4* wg = (const float4*)(first ? w3r_ : w3o_);
        float4 acc = {0.f,0.f,0.f,0.f};
#pragma unroll 8
        for (int k = 0; k < HID; k++) {
            float a = sX3[n * SH + k];
            FMA4(acc, a, wg[k * 8 + fq]);
        }
        if (first) ((float4*)(sW3r + n * SH))[fq] = acc;
        else       ((float4*)(sW3o + n * SH))[fq] = acc;
    } else if (tid >= 160 && tid < 160 + K2) {
        int l = tid - 160;
        float s = 0.f;
#pragma unroll
        for (int m = 0; m < K2; m++) s += sA3[l * K2 + m];
        s -= sA3[l * (K2 + 1)];
        srowm[l] = 1.f / (sqrtf(s) + EPSF);
    } else if (tid == 200) {
        float num2 = 0.f;
#pragma unroll
        for (int k = 0; k < K2; k++) num2 += sA3[k * (K2 + 1)];
        wsg[g] = -(sc[0] / sc[1]) + sc[2] - num2 / sc[5] + sc[6];
    }
    __syncthreads();

    // ---- p15: X4 = adj2n @ XW3r + XW3o + b3  [folded, diag skipped] ----
    if (tid < 80) {
        int k = tid >> 3, fq = tid & 7;
        float4 acc = {0.f,0.f,0.f,0.f};
#pragma unroll
        for (int l = 0; l < K2; l++) {
            float a = (l == k) ? 0.f : sA3[k * K2 + l];
            float4 w = ((const float4*)(sW3r + l * SH))[fq];
            FMA4(acc, a * srowm[l], w);
        }
        float4 bb = ((const float4*)b3_)[fq];
        float4 oo = ((const float4*)(sW3o + k * SH))[fq];
        float rk = srowm[k];
        float4 r;
        r.x = fmaf(rk, acc.x, oo.x + bb.x);
        r.y = fmaf(rk, acc.y, oo.y + bb.y);
        r.z = fmaf(rk, acc.z, oo.z + bb.z);
        r.w = fmaf(rk, acc.w, oo.w + bb.w);
        ((float4*)(sX4 + k * SH))[fq] = r;
    }
    __syncthreads();

    // ---- p16: mean pool + MLP head (wave 0, shuffle-based) ----
    if (wid == 0) {
        int f = lane & 31;
        float pool = 0.f;
#pragma unroll
        for (int n = 0; n < K2; n++) pool += sX4[n * SH + f];
        pool *= (1.f / K2);
        float acc = b_l1[f];
#pragma unroll
        for (int j = 0; j < HID; j++)
            acc = fmaf(__shfl(pool, j, 64), w_l1[j * HID + f], acc);
        float t1 = fmaxf(acc, 0.f);
        int o = (lane < OUTC) ? lane : 0;
        float acc2 = b_l2[o];
#pragma unroll
        for (int j = 0; j < HID; j++)
            acc2 = fmaf(__shfl(t1, j, 64), w_l2[j * OUTC + o], acc2);
        if (lane < OUTC) out[(size_t)g * OUTC + lane] = acc2;
    }
}

__global__ void loss_reduce(const float* __restrict__ wsg, float* __restrict__ out)
{
    __shared__ float sred[4];
    int tid = threadIdx.x;
    float s = 0.f;
    for (int i = tid; i < Bg; i += NT) s += wsg[i];
    s = wave_red(s);
    if ((tid & 63) == 0) sred[tid >> 6] = s;
    __syncthreads();
    if (tid == 0) out[(size_t)Bg * OUTC] = (sred[0] + sred[1] + sred[2] + sred[3]) * (1.f / Bg);
}

extern "C" void kernel_launch(void* const* d_in, const int* in_sizes, int n_in,
                              void* d_out, int out_size, void* d_ws, size_t ws_size,
                              hipStream_t stream)
{
    const float* x    = (const float*)d_in[0];
    const int*   ei   = (const int*)  d_in[1];
    // d_in[2] = batch (unused: graphs are contiguous blocks of NPG nodes)
    const float* w_c1 = (const float*)d_in[3];
    const float* b_c1 = (const float*)d_in[4];
    const float* w_p1 = (const float*)d_in[5];
    const float* b_p1 = (const float*)d_in[6];
    const float* w2r  = (const float*)d_in[7];
    const float* b2   = (const float*)d_in[8];
    const float* w2o  = (const float*)d_in[9];
    const float* w_p2 = (const float*)d_in[10];
    const float* b_p2 = (const float*)d_in[11];
    const float* w3r  = (const float*)d_in[12];
    const float* b3   = (const float*)d_in[13];
    const float* w3o  = (const float*)d_in[14];
    const float* w_l1 = (const float*)d_in[15];
    const float* b_l1 = (const float*)d_in[16];
    const float* w_l2 = (const float*)d_in[17];
    const float* b_l2 = (const float*)d_in[18];
    float* out = (float*)d_out;
    float* wsg = (float*)d_ws;

    hipLaunchKernelGGL(mincut_fused, dim3(Bg), dim3(NT), 0, stream,
                       x, ei, w_c1, b_c1, w_p1, b_p1, w2r, b2, w2o,
                       w_p2, b_p2, w3r, b3, w3o, w_l1, b_l1, w_l2, b_l2,
                       out, wsg);
    hipLaunchKernelGGL(loss_reduce, dim3(1), dim3(NT), 0, stream, wsg, out);
}

// Round 11
// 246.548 us; speedup vs baseline: 1.2774x; 1.0476x over previous
//
#include <hip/hip_runtime.h>

#define NT 256

constexpr int Bg   = 8192;      // graphs
constexpr int NPG  = 40;
constexpr int EPG  = 640;
constexpr int IN_  = 64;
constexpr int HID  = 32;
constexpr int K1   = 20;
constexpr int K2   = 10;
constexpr int OUTC = 10;
constexpr int NE   = Bg * NPG * 16;
constexpr int SX   = 68;        // padded X row stride
constexpr int SH   = 36;        // padded 32-wide row stride
constexpr float EPSF = 1e-15f;

#define FMA4(acc, a, b) do { \
    float _s = (a); \
    acc.x = fmaf(_s, (b).x, acc.x); \
    acc.y = fmaf(_s, (b).y, acc.y); \
    acc.z = fmaf(_s, (b).z, acc.z); \
    acc.w = fmaf(_s, (b).w, acc.w); } while (0)

__device__ __forceinline__ float wave_red(float v) {
#pragma unroll
    for (int off = 32; off > 0; off >>= 1) v += __shfl_down(v, off, 64);
    return v;
}

// LDS overlay (floats) — 23.7 KB total -> 6 blocks/CU:
//  sA [1600]: raw A (p0-p6); A2 raw @0(400) p7+; A3 raw @400(100) p13+
//  sB [2720]: X stage stride 68 (p0-p1); H@0(1440) p1b-p3; S1@0(800) p4-p7;
//             AS@800(800) p6-p7; S2@800(200) p11+; AS2@1000(200) p12-p13;
//             X3@1200(360) p12-p14; X4@1200(360) p15+; SS/SS2@1600(400);
//             X2@2000(720) p7+
//  sXd[1440]: Xd p3-p7; XW2r@0(720)+XW2o@720(720) p8-pC; XW3r@0+XW3o@360 p14+
// NOTE: __launch_bounds__(256,4) — (256,6) forced 40 VGPR + 38KB/block spill (r4).
// BUG FIXED from r9: p12 SS2 write was sSS[oo-200] with oo already o-200
// (negative index -> corrupted X3 at sB[1400,1500)). Now sSS[oo].
__global__ __launch_bounds__(NT, 4)
void mincut_fused(const float* __restrict__ x, const int* __restrict__ ei,
                  const float* __restrict__ w_c1, const float* __restrict__ b_c1,
                  const float* __restrict__ w_p1, const float* __restrict__ b_p1,
                  const float* __restrict__ w2r_, const float* __restrict__ b2_,
                  const float* __restrict__ w2o_,
                  const float* __restrict__ w_p2, const float* __restrict__ b_p2,
                  const float* __restrict__ w3r_, const float* __restrict__ b3_,
                  const float* __restrict__ w3o_,
                  const float* __restrict__ w_l1, const float* __restrict__ b_l1,
                  const float* __restrict__ w_l2, const float* __restrict__ b_l2,
                  float* __restrict__ out, float* __restrict__ wsg)
{
    __shared__ __align__(16) float sA[NPG * NPG];    // 1600
    __shared__ __align__(16) float sB[NPG * SX];     // 2720
    __shared__ __align__(16) float sXd[NPG * SH];    // 1440
    __shared__ __align__(16) float sdinv[NPG];
    __shared__ __align__(16) float srowsA[NPG];
    __shared__ __align__(16) float srowm[NPG];
    __shared__ __align__(16) float sden[NPG];
    __shared__ __align__(16) float sc[8];
    // sc: [0]num1 [1]den1 [2]o1 [5]den2 [6]o2

    float* sA2  = sA;            // 20x20 raw
    float* sA3  = sA + 400;      // 10x10 raw
    float* sH   = sB;            // 40xSH
    float* sS   = sB;            // 40x20
    float* sAS  = sB + 800;      // 40x20
    float* sS2  = sB + 800;      // 20x10
    float* sAS2 = sB + 1000;     // 20x10
    float* sX3  = sB + 1200;     // 10xSH
    float* sX4  = sB + 1200;     // 10xSH (after X3 dead)
    float* sSS  = sB + 1600;     // 400 (SS then SS2)
    float* sX2  = sB + 2000;     // 20xSH
    float* sXw2r= sXd;           // 20xSH
    float* sXw2o= sXd + 720;     // 20xSH
    float* sW3r = sXd;           // 10xSH
    float* sW3o = sXd + 360;     // 10xSH

    const int g    = blockIdx.x;
    const int tid  = threadIdx.x;
    const int lane = tid & 63;
    const int wid  = tid >> 6;

    // ---- p0: edges -> regs, zero A, stage X ----
    int er0, ec0, er1, ec1, er2 = -1, ec2 = 0;
    {
        const int eb = g * EPG, nb = g * NPG;
        int e = eb + tid;
        er0 = ei[e] - nb; ec0 = ei[NE + e] - nb;
        e += NT;
        er1 = ei[e] - nb; ec1 = ei[NE + e] - nb;
        if (tid + 2 * NT < EPG) {
            e += NT;
            er2 = ei[e] - nb; ec2 = ei[NE + e] - nb;
        }
    }
    for (int i = tid; i < NPG * NPG; i += NT) sA[i] = 0.f;
    {
        const float4* xg = (const float4*)(x + (size_t)g * (NPG * IN_));
        for (int i = tid; i < NPG * (IN_ / 4); i += NT) {
            int n = i >> 4, k = i & 15;
            ((float4*)(sB + n * SX))[k] = xg[i];
        }
    }
    __syncthreads();

    // ---- p1: adj scatter + H = X @ W1 (held in registers) ----
    atomicAdd(&sA[er0 * NPG + ec0], 1.f);
    atomicAdd(&sA[er1 * NPG + ec1], 1.f);
    if (er2 >= 0) atomicAdd(&sA[er2 * NPG + ec2], 1.f);

    float4 hacc0 = {0.f,0.f,0.f,0.f}, hacc1 = {0.f,0.f,0.f,0.f};
    if (tid < 160) {
        int np = tid >> 3, fq = tid & 7;
        int n0 = 2 * np, n1 = n0 + 1;
        const float4* a0p = (const float4*)(sB + n0 * SX);
        const float4* a1p = (const float4*)(sB + n1 * SX);
        const float4* wg  = (const float4*)w_c1;
#pragma unroll 4
        for (int kk = 0; kk < IN_ / 4; kk++) {
            float4 a0 = a0p[kk], a1 = a1p[kk];
            float4 w0 = wg[(4*kk+0)*8 + fq];
            float4 w1 = wg[(4*kk+1)*8 + fq];
            float4 w2 = wg[(4*kk+2)*8 + fq];
            float4 w3 = wg[(4*kk+3)*8 + fq];
            FMA4(hacc0, a0.x, w0); FMA4(hacc0, a0.y, w1);
            FMA4(hacc0, a0.z, w2); FMA4(hacc0, a0.w, w3);
            FMA4(hacc1, a1.x, w0); FMA4(hacc1, a1.y, w1);
            FMA4(hacc1, a1.z, w2); FMA4(hacc1, a1.w, w3);
        }
    }
    __syncthreads();

    // ---- p1b: write H into dead X region ; degrees (spare threads) ----
    if (tid < 160) {
        int np = tid >> 3, fq = tid & 7;
        int n0 = 2 * np, n1 = n0 + 1;
        ((float4*)(sH + n0 * SH))[fq] = hacc0;
        ((float4*)(sH + n1 * SH))[fq] = hacc1;
    } else if (tid < 200) {
        int c = tid - 160; float s = 0.f;
#pragma unroll
        for (int r = 0; r < NPG; r++) s += sA[r * NPG + c];
        sdinv[c] = rsqrtf(s + 1.f);
    } else if (tid < 240) {
        int n = tid - 200; float s = 0.f;
#pragma unroll
        for (int m = 0; m < NPG; m++) s += sA[n * NPG + m];
        srowsA[n] = s;
    }
    __syncthreads();

    // ---- p3: Xd = relu(D^-1/2 (A+I) D^-1/2 H + b1)  [dinv folded] ----
    if (tid < 160) {
        int cp = tid >> 3, fq = tid & 7;
        int c0 = 2 * cp, c1 = c0 + 1;
        float4 acc0 = {0.f,0.f,0.f,0.f}, acc1 = {0.f,0.f,0.f,0.f};
#pragma unroll 8
        for (int r = 0; r < NPG; r++) {
            float2 a2 = *(const float2*)&sA[r * NPG + c0];
            float dv = sdinv[r];
            float4 bv = ((const float4*)(sH + r * SH))[fq];
            FMA4(acc0, a2.x * dv, bv);
            FMA4(acc1, a2.y * dv, bv);
        }
        float4 bb = ((const float4*)b_c1)[fq];
        float4 h0 = ((const float4*)(sH + c0 * SH))[fq];
        float4 h1 = ((const float4*)(sH + c1 * SH))[fq];
        float d0 = sdinv[c0], d1 = sdinv[c1];
        float4 r0, r1;
        r0.x = fmaxf(fmaf(d0, fmaf(d0, h0.x, acc0.x), bb.x), 0.f);
        r0.y = fmaxf(fmaf(d0, fmaf(d0, h0.y, acc0.y), bb.y), 0.f);
        r0.z = fmaxf(fmaf(d0, fmaf(d0, h0.z, acc0.z), bb.z), 0.f);
        r0.w = fmaxf(fmaf(d0, fmaf(d0, h0.w, acc0.w), bb.w), 0.f);
        r1.x = fmaxf(fmaf(d1, fmaf(d1, h1.x, acc1.x), bb.x), 0.f);
        r1.y = fmaxf(fmaf(d1, fmaf(d1, h1.y, acc1.y), bb.y), 0.f);
        r1.z = fmaxf(fmaf(d1, fmaf(d1, h1.z, acc1.z), bb.z), 0.f);
        r1.w = fmaxf(fmaf(d1, fmaf(d1, h1.w, acc1.w), bb.w), 0.f);
        ((float4*)(sXd + c0 * SH))[fq] = r0;
        ((float4*)(sXd + c1 * SH))[fq] = r1;
    }
    __syncthreads();

    // ---- p4: S1 logits = Xd @ Wp1 + bp1  (S1 overwrites dead H) ----
    if (tid < 100) {
        int np = tid / 5, lq = tid - np * 5;
        int n0 = 2 * np, n1 = n0 + 1;
        const float4* wg = (const float4*)w_p1;
        float4 bb = ((const float4*)b_p1)[lq];
        float4 acc0 = bb, acc1 = bb;
#pragma unroll 8
        for (int k = 0; k < HID; k++) {
            float a0 = sXd[n0 * SH + k];
            float a1 = sXd[n1 * SH + k];
            float4 w = wg[k * 5 + lq];
            FMA4(acc0, a0, w); FMA4(acc1, a1, w);
        }
        ((float4*)(sS + n0 * K1))[lq] = acc0;
        ((float4*)(sS + n1 * K1))[lq] = acc1;
    }
    __syncthreads();

    // ---- p5: softmax1 ----
    if (tid < NPG) {
        float* row = sS + tid * K1;
        float v[K1]; float m = -3.0e38f;
#pragma unroll
        for (int k = 0; k < K1; k++) { v[k] = row[k]; m = fmaxf(m, v[k]); }
        float ssum = 0.f;
#pragma unroll
        for (int k = 0; k < K1; k++) { v[k] = __expf(v[k] - m); ssum += v[k]; }
        float inv = 1.f / ssum;
#pragma unroll
        for (int k = 0; k < K1; k++) row[k] = v[k] * inv;
    }
    __syncthreads();

    // ---- p6: AS = A @ S ; SS = S^T S ----
    if (tid < 100) {
        int np = tid / 5, lq = tid - np * 5;
        int n0 = 2 * np, n1 = n0 + 1;
        const float4* sb4 = (const float4*)sS;
        float4 acc0 = {0.f,0.f,0.f,0.f}, acc1 = {0.f,0.f,0.f,0.f};
#pragma unroll
        for (int m4 = 0; m4 < NPG / 4; m4++) {
            float4 a0 = *(const float4*)&sA[n0 * NPG + 4 * m4];
            float4 a1 = *(const float4*)&sA[n1 * NPG + 4 * m4];
            float4 b0 = sb4[(4*m4+0)*5 + lq];
            float4 b1 = sb4[(4*m4+1)*5 + lq];
            float4 b2v = sb4[(4*m4+2)*5 + lq];
            float4 b3v = sb4[(4*m4+3)*5 + lq];
            FMA4(acc0, a0.x, b0); FMA4(acc0, a0.y, b1);
            FMA4(acc0, a0.z, b2v); FMA4(acc0, a0.w, b3v);
            FMA4(acc1, a1.x, b0); FMA4(acc1, a1.y, b1);
            FMA4(acc1, a1.z, b2v); FMA4(acc1, a1.w, b3v);
        }
        ((float4*)(sAS + n0 * K1))[lq] = acc0;
        ((float4*)(sAS + n1 * K1))[lq] = acc1;
    } else if (tid < 150) {
        int oo = tid - 100;
        int kp = oo / 5, lq = oo - kp * 5;
        int k0 = 2 * kp, k1 = k0 + 1;
        float4 acc0 = {0.f,0.f,0.f,0.f}, acc1 = {0.f,0.f,0.f,0.f};
#pragma unroll 8
        for (int n = 0; n < NPG; n++) {
            float2 s2v = *(const float2*)&sS[n * K1 + k0];
            float4 bv = ((const float4*)(sS + n * K1))[lq];
            FMA4(acc0, s2v.x, bv); FMA4(acc1, s2v.y, bv);
        }
        ((float4*)(sSS + k0 * K1))[lq] = acc0;
        ((float4*)(sSS + k1 * K1))[lq] = acc1;
    }
    __syncthreads();

    // ---- p7: A2 = S^T AS (raw) ; X2 = S^T Xd ; den1 terms ----
    if (tid < 50) {
        int kp = tid / 5, lq = tid - kp * 5;
        int k0 = 2 * kp, k1 = k0 + 1;
        float4 acc0 = {0.f,0.f,0.f,0.f}, acc1 = {0.f,0.f,0.f,0.f};
#pragma unroll 8
        for (int n = 0; n < NPG; n++) {
            float2 s2v = *(const float2*)&sS[n * K1 + k0];
            float4 bv = ((const float4*)(sAS + n * K1))[lq];
            FMA4(acc0, s2v.x, bv); FMA4(acc1, s2v.y, bv);
        }
        ((float4*)(sA2 + k0 * K1))[lq] = acc0;
        ((float4*)(sA2 + k1 * K1))[lq] = acc1;
    } else if (tid < 130) {
        int oo = tid - 50;
        int kp = oo >> 3, fq = oo & 7;
        int k0 = 2 * kp, k1 = k0 + 1;
        float4 acc0 = {0.f,0.f,0.f,0.f}, acc1 = {0.f,0.f,0.f,0.f};
#pragma unroll 8
        for (int n = 0; n < NPG; n++) {
            float2 s2v = *(const float2*)&sS[n * K1 + k0];
            float4 bv = ((const float4*)(sXd + n * SH))[fq];
            FMA4(acc0, s2v.x, bv); FMA4(acc1, s2v.y, bv);
        }
        ((float4*)(sX2 + k0 * SH))[fq] = acc0;
        ((float4*)(sX2 + k1 * SH))[fq] = acc1;
    } else if (tid < 170) {
        int n = tid - 130;
        float s2 = 0.f;
#pragma unroll
        for (int k = 0; k < K1; k++) { float v = sS[n * K1 + k]; s2 = fmaf(v, v, s2); }
        sden[n] = srowsA[n] * s2;
    }
    __syncthreads();

    // ---- p8: stats (3 waves) + XW2r/XW2o strided matmuls ----
    if (wid == 0) {              // closed-form ortho1 from SS
        float f = 0.f, tr = 0.f;
        for (int i = lane; i < K1 * K1; i += 64) {
            float t = sSS[i];
            f = fmaf(t, t, f);
            if (i % (K1 + 1) == 0) tr += t;
        }
        f = wave_red(f); tr = wave_red(tr);
        if (lane == 0)
            sc[2] = sqrtf(fmaxf(2.f - 2.f * tr / (sqrtf(f) * 4.47213595499958f), 0.f));
    } else if (wid == 1) {       // num1 = trace(A2) ; rownorm1 (A2 kept raw)
        float v = 0.f;
        if (lane < K1) {
            float s = 0.f;
#pragma unroll
            for (int l = 0; l < K1; l++) s += sA2[lane * K1 + l];
            float d = sA2[lane * (K1 + 1)];
            srowm[lane] = 1.f / (sqrtf(s - d) + EPSF);
            v = d;
        }
        v = wave_red(v);
        if (lane == 0) sc[0] = v;
    } else if (wid == 2) {       // den1
        float v = (lane < NPG) ? sden[lane] : 0.f;
        v = wave_red(v);
        if (lane == 0) sc[1] = v;
    }
    for (int o = tid; o < 320; o += NT) {
        int first = o < 160; int m = first ? o : o - 160;
        int n = m >> 3, fq = m & 7;
        const float4* wg = (const float4*)(first ? w2r_ : w2o_);
        float4 acc = {0.f,0.f,0.f,0.f};
#pragma unroll 8
        for (int k = 0; k < HID; k++) {
            float a = sX2[n * SH + k];
            FMA4(acc, a, wg[k * 8 + fq]);
        }
        ((float4*)((first ? sXw2r : sXw2o) + n * SH))[fq] = acc;
    }
    __syncthreads();

    // ---- pC: X2' = relu(adj1n @ XW2r + XW2o + b2)  [folded, diag skipped] --
    if (tid < 160) {
        int k = tid >> 3, fq = tid & 7;
        float4 acc = {0.f,0.f,0.f,0.f};
#pragma unroll
        for (int l = 0; l < K1; l++) {
            float a = (l == k) ? 0.f : sA2[k * K1 + l];
            float4 w = ((const float4*)(sXw2r + l * SH))[fq];
            FMA4(acc, a * srowm[l], w);
        }
        float4 bb = ((const float4*)b2_)[fq];
        float4 oo = ((const float4*)(sXw2o + k * SH))[fq];
        float rk = srowm[k];
        float4 r;
        r.x = fmaxf(fmaf(rk, acc.x, oo.x + bb.x), 0.f);
        r.y = fmaxf(fmaf(rk, acc.y, oo.y + bb.y), 0.f);
        r.z = fmaxf(fmaf(rk, acc.z, oo.z + bb.z), 0.f);
        r.w = fmaxf(fmaf(rk, acc.w, oo.w + bb.w), 0.f);
        ((float4*)(sX2 + k * SH))[fq] = r;
    }
    __syncthreads();

    // ---- p11: S2 logits + softmax2 fused (one thread per row) ----
    if (tid < K1) {
        float acc[K2];
#pragma unroll
        for (int q = 0; q < K2; q++) acc[q] = b_p2[q];
#pragma unroll 8
        for (int j = 0; j < HID; j++) {
            float a = sX2[tid * SH + j];
#pragma unroll
            for (int q = 0; q < K2; q++) acc[q] = fmaf(a, w_p2[j * K2 + q], acc[q]);
        }
        float m = -3.0e38f;
#pragma unroll
        for (int q = 0; q < K2; q++) m = fmaxf(m, acc[q]);
        float ssum = 0.f;
#pragma unroll
        for (int q = 0; q < K2; q++) { acc[q] = __expf(acc[q] - m); ssum += acc[q]; }
        float inv = 1.f / ssum;
#pragma unroll
        for (int q = 0; q < K2; q++) sS2[tid * K2 + q] = acc[q] * inv;
    }
    __syncthreads();

    // ---- p12: AS2 = adj1n@S2 ; SS2 ; X3 = S2^T X2' ; den2 terms ----
    for (int o = tid; o < 400; o += NT) {
        if (o < 200) {
            int n = o / K2, l = o - n * K2;
            float acc = 0.f;
#pragma unroll
            for (int m = 0; m < K1; m++) {
                float a = (m == n) ? 0.f : sA2[n * K1 + m];
                acc = fmaf(a * srowm[m], sS2[m * K2 + l], acc);
            }
            sAS2[n * K2 + l] = acc * srowm[n];
        } else if (o < 300) {
            int oo = o - 200; int k = oo / K2, l = oo - k * K2;
            float acc = 0.f;
#pragma unroll
            for (int n = 0; n < K1; n++) acc = fmaf(sS2[n * K2 + k], sS2[n * K2 + l], acc);
            sSS[oo] = acc;
        } else if (o < 380) {
            int oo = o - 300; int k = oo >> 3, fq = oo & 7;
            float4 acc = {0.f,0.f,0.f,0.f};
#pragma unroll
            for (int n = 0; n < K1; n++) {
                float a = sS2[n * K2 + k];
                float4 bv = ((const float4*)(sX2 + n * SH))[fq];
                FMA4(acc, a, bv);
            }
            ((float4*)(sX3 + k * SH))[fq] = acc;
        } else {
            int n = o - 380;
            float da = 0.f, s2 = 0.f;
#pragma unroll
            for (int l = 0; l < K1; l++) {
                float a = (l == n) ? 0.f : sA2[n * K1 + l];
                da = fmaf(a, srowm[l], da);
            }
            da *= srowm[n];
#pragma unroll
            for (int q = 0; q < K2; q++) { float v = sS2[n * K2 + q]; s2 = fmaf(v, v, s2); }
            sden[n] = da * s2;
        }
    }
    __syncthreads();

    // ---- p13: A3 = S2^T AS2 (raw) ; den2 reduce ; ortho2 closed-form ----
    if (tid < K2 * K2) {
        int k = tid / K2, l = tid - k * K2;
        float acc = 0.f;
#pragma unroll
        for (int n = 0; n < K1; n++) acc = fmaf(sS2[n * K2 + k], sAS2[n * K2 + l], acc);
        sA3[tid] = acc;
    } else if (wid == 2) {
        float v = (lane < K1) ? sden[lane] : 0.f;
        v = wave_red(v);
        if (lane == 0) sc[5] = v;
    } else if (wid == 3) {
        float f = 0.f, tr = 0.f;
        for (int i = lane; i < K2 * K2; i += 64) {
            float t = sSS[i];
            f = fmaf(t, t, f);
            if (i % (K2 + 1) == 0) tr += t;
        }
        f = wave_red(f); tr = wave_red(tr);
        if (lane == 0)
            sc[6] = sqrtf(fmaxf(2.f - 2.f * tr / (sqrtf(f) * 3.1622776601683795f), 0.f));
    }
    __syncthreads();

    // ---- p14: XW3r/XW3o ; rownorm2 ; loss write ----
    if (tid < 160) {
        bool first = (tid < 80);
        int oo = first ? tid : tid - 80;
        int n = oo >> 3, fq = oo & 7;
        const float4* wg = (const float4*)(first ? w3r_ : w3o_);
        float4 acc = {0.f,0.f,0.f,0.f};
#pragma unroll 8
        for (int k = 0; k < HID; k++) {
            float a = sX3[n * SH + k];
            FMA4(acc, a, wg[k * 8 + fq]);
        }
        if (first) ((float4*)(sW3r + n * SH))[fq] = acc;
        else       ((float4*)(sW3o + n * SH))[fq] = acc;
    } else if (tid >= 160 && tid < 160 + K2) {
        int l = tid - 160;
        float s = 0.f;
#pragma unroll
        for (int m = 0; m < K2; m++) s += sA3[l * K2 + m];
        s -= sA3[l * (K2 + 1)];
        srowm[l] = 1.f / (sqrtf(s) + EPSF);
    } else if (tid == 200) {
        float num2 = 0.f;
#pragma unroll
        for (int k = 0; k < K2; k++) num2 += sA3[k * (K2 + 1)];
        wsg[g] = -(sc[0] / sc[1]) + sc[2] - num2 / sc[5] + sc[6];
    }
    __syncthreads();

    // ---- p15: X4 = adj2n @ XW3r + XW3o + b3  [folded, diag skipped] ----
    if (tid < 80) {
        int k = tid >> 3, fq = tid & 7;
        float4 acc = {0.f,0.f,0.f,0.f};
#pragma unroll
        for (int l = 0; l < K2; l++) {
            float a = (l == k) ? 0.f : sA3[k * K2 + l];
            float4 w = ((const float4*)(sW3r + l * SH))[fq];
            FMA4(acc, a * srowm[l], w);
        }
        float4 bb = ((const float4*)b3_)[fq];
        float4 oo = ((const float4*)(sW3o + k * SH))[fq];
        float rk = srowm[k];
        float4 r;
        r.x = fmaf(rk, acc.x, oo.x + bb.x);
        r.y = fmaf(rk, acc.y, oo.y + bb.y);
        r.z = fmaf(rk, acc.z, oo.z + bb.z);
        r.w = fmaf(rk, acc.w, oo.w + bb.w);
        ((float4*)(sX4 + k * SH))[fq] = r;
    }
    __syncthreads();

    // ---- p16: mean pool + MLP head (wave 0, shuffle-based) ----
    if (wid == 0) {
        int f = lane & 31;
        float pool = 0.f;
#pragma unroll
        for (int n = 0; n < K2; n++) pool += sX4[n * SH + f];
        pool *= (1.f / K2);
        float acc = b_l1[f];
#pragma unroll
        for (int j = 0; j < HID; j++)
            acc = fmaf(__shfl(pool, j, 64), w_l1[j * HID + f], acc);
        float t1 = fmaxf(acc, 0.f);
        int o = (lane < OUTC) ? lane : 0;
        float acc2 = b_l2[o];
#pragma unroll
        for (int j = 0; j < HID; j++)
            acc2 = fmaf(__shfl(t1, j, 64), w_l2[j * OUTC + o], acc2);
        if (lane < OUTC) out[(size_t)g * OUTC + lane] = acc2;
    }
}

__global__ void loss_reduce(const float* __restrict__ wsg, float* __restrict__ out)
{
    __shared__ float sred[4];
    int tid = threadIdx.x;
    float s = 0.f;
    for (int i = tid; i < Bg; i += NT) s += wsg[i];
    s = wave_red(s);
    if ((tid & 63) == 0) sred[tid >> 6] = s;
    __syncthreads();
    if (tid == 0) out[(size_t)Bg * OUTC] = (sred[0] + sred[1] + sred[2] + sred[3]) * (1.f / Bg);
}

extern "C" void kernel_launch(void* const* d_in, const int* in_sizes, int n_in,
                              void* d_out, int out_size, void* d_ws, size_t ws_size,
                              hipStream_t stream)
{
    const float* x    = (const float*)d_in[0];
    const int*   ei   = (const int*)  d_in[1];
    // d_in[2] = batch (unused: graphs are contiguous blocks of NPG nodes)
    const float* w_c1 = (const float*)d_in[3];
    const float* b_c1 = (const float*)d_in[4];
    const float* w_p1 = (const float*)d_in[5];
    const float* b_p1 = (const float*)d_in[6];
    const float* w2r  = (const float*)d_in[7];
    const float* b2   = (const float*)d_in[8];
    const float* w2o  = (const float*)d_in[9];
    const float* w_p2 = (const float*)d_in[10];
    const float* b_p2 = (const float*)d_in[11];
    const float* w3r  = (const float*)d_in[12];
    const float* b3   = (const float*)d_in[13];
    const float* w3o  = (const float*)d_in[14];
    const float* w_l1 = (const float*)d_in[15];
    const float* b_l1 = (const float*)d_in[16];
    const float* w_l2 = (const float*)d_in[17];
    const float* b_l2 = (const float*)d_in[18];
    float* out = (float*)d_out;
    float* wsg = (float*)d_ws;

    hipLaunchKernelGGL(mincut_fused, dim3(Bg), dim3(NT), 0, stream,
                       x, ei, w_c1, b_c1, w_p1, b_p1, w2r, b2, w2o,
                       w_p2, b_p2, w3r, b3, w3o, w_l1, b_l1, w_l2, b_l2,
                       out, wsg);
    hipLaunchKernelGGL(loss_reduce, dim3(1), dim3(NT), 0, stream, wsg, out);
}

// Round 12
// 245.424 us; speedup vs baseline: 1.2832x; 1.0046x over previous
//
#include <hip/hip_runtime.h>

#define NT 256

constexpr int Bg   = 8192;      // graphs
constexpr int NPG  = 40;
constexpr int EPG  = 640;
constexpr int IN_  = 64;
constexpr int HID  = 32;
constexpr int K1   = 20;
constexpr int K2   = 10;
constexpr int OUTC = 10;
constexpr int NE   = Bg * NPG * 16;
constexpr int SH   = 36;        // padded 32-wide row stride
constexpr float EPSF = 1e-15f;

#define FMA4(acc, a, b) do { \
    float _s = (a); \
    acc.x = fmaf(_s, (b).x, acc.x); \
    acc.y = fmaf(_s, (b).y, acc.y); \
    acc.z = fmaf(_s, (b).z, acc.z); \
    acc.w = fmaf(_s, (b).w, acc.w); } while (0)

__device__ __forceinline__ float wave_red(float v) {
#pragma unroll
    for (int off = 32; off > 0; off >>= 1) v += __shfl_down(v, off, 64);
    return v;
}

// LDS overlay (floats) — ~20.9 KB total -> 7 blocks/CU (was 24.1 -> 6):
//  sA [1600]: raw A (p0-p6); A2 raw @0(400) p7+; X2 @400(720) p7-p12;
//             A3 raw @400(100) p13+ (reuses dead X2)
//  sB [2000]: H@0(1440) p1b-p3; S1@0(800) p4-p7; AS@800(1600) p6-p7;
//             S2@800(200) p11+; AS2@1000(200) p12-p13; X3@1200(360) p12-p14;
//             X4@1200(360) p15+; SS/SS2@1600(400) p6+/p12+
//  sXd[1440]: Xd p3-p7; XW2r@0(720)+XW2o@720(720) p8-pC; XW3r@0+XW3o@360 p14+
//  X is NOT LDS-staged (r11 change): p1 reads X from global — 8x redundancy
//  absorbed by L1/L2; buys the sB shrink that funds the 7th resident block.
// NOTE: __launch_bounds__(256,4) — (256,6) forced 40 VGPR + 38KB/block spill (r4).
__global__ __launch_bounds__(NT, 4)
void mincut_fused(const float* __restrict__ x, const int* __restrict__ ei,
                  const float* __restrict__ w_c1, const float* __restrict__ b_c1,
                  const float* __restrict__ w_p1, const float* __restrict__ b_p1,
                  const float* __restrict__ w2r_, const float* __restrict__ b2_,
                  const float* __restrict__ w2o_,
                  const float* __restrict__ w_p2, const float* __restrict__ b_p2,
                  const float* __restrict__ w3r_, const float* __restrict__ b3_,
                  const float* __restrict__ w3o_,
                  const float* __restrict__ w_l1, const float* __restrict__ b_l1,
                  const float* __restrict__ w_l2, const float* __restrict__ b_l2,
                  float* __restrict__ out, float* __restrict__ wsg)
{
    __shared__ __align__(16) float sA[NPG * NPG];    // 1600
    __shared__ __align__(16) float sB[2000];
    __shared__ __align__(16) float sXd[NPG * SH];    // 1440
    __shared__ __align__(16) float sdinv[NPG];
    __shared__ __align__(16) float srowsA[NPG];
    __shared__ __align__(16) float srowm[NPG];
    __shared__ __align__(16) float sden[NPG];
    __shared__ __align__(16) float sc[8];
    // sc: [0]num1 [1]den1 [2]o1 [5]den2 [6]o2

    float* sA2  = sA;            // 20x20 raw
    float* sX2  = sA + 400;      // 20xSH  (p7-p12)
    float* sA3  = sA + 400;      // 10x10 raw (p13+, X2 dead)
    float* sH   = sB;            // 40xSH
    float* sS   = sB;            // 40x20
    float* sAS  = sB + 800;      // 40x20
    float* sS2  = sB + 800;      // 20x10
    float* sAS2 = sB + 1000;     // 20x10
    float* sX3  = sB + 1200;     // 10xSH
    float* sX4  = sB + 1200;     // 10xSH (after X3 dead)
    float* sSS  = sB + 1600;     // 400 (SS then SS2)
    float* sXw2r= sXd;           // 20xSH
    float* sXw2o= sXd + 720;     // 20xSH
    float* sW3r = sXd;           // 10xSH
    float* sW3o = sXd + 360;     // 10xSH

    const int g    = blockIdx.x;
    const int tid  = threadIdx.x;
    const int lane = tid & 63;
    const int wid  = tid >> 6;

    // ---- p0: edges -> regs, zero A ----
    int er0, ec0, er1, ec1, er2 = -1, ec2 = 0;
    {
        const int eb = g * EPG, nb = g * NPG;
        int e = eb + tid;
        er0 = ei[e] - nb; ec0 = ei[NE + e] - nb;
        e += NT;
        er1 = ei[e] - nb; ec1 = ei[NE + e] - nb;
        if (tid + 2 * NT < EPG) {
            e += NT;
            er2 = ei[e] - nb; ec2 = ei[NE + e] - nb;
        }
    }
    for (int i = tid; i < NPG * NPG; i += NT) sA[i] = 0.f;
    __syncthreads();

    // ---- p1: adj scatter + H = X @ W1 (X from global, held in registers) ----
    atomicAdd(&sA[er0 * NPG + ec0], 1.f);
    atomicAdd(&sA[er1 * NPG + ec1], 1.f);
    if (er2 >= 0) atomicAdd(&sA[er2 * NPG + ec2], 1.f);

    float4 hacc0 = {0.f,0.f,0.f,0.f}, hacc1 = {0.f,0.f,0.f,0.f};
    if (tid < 160) {
        int np = tid >> 3, fq = tid & 7;
        int n0 = 2 * np, n1 = n0 + 1;
        const float4* x0 = (const float4*)(x + (size_t)g * (NPG * IN_) + n0 * IN_);
        const float4* x1 = (const float4*)(x + (size_t)g * (NPG * IN_) + n1 * IN_);
        const float4* wg = (const float4*)w_c1;
#pragma unroll 4
        for (int kk = 0; kk < IN_ / 4; kk++) {
            float4 a0 = x0[kk], a1 = x1[kk];
            float4 w0 = wg[(4*kk+0)*8 + fq];
            float4 w1 = wg[(4*kk+1)*8 + fq];
            float4 w2 = wg[(4*kk+2)*8 + fq];
            float4 w3 = wg[(4*kk+3)*8 + fq];
            FMA4(hacc0, a0.x, w0); FMA4(hacc0, a0.y, w1);
            FMA4(hacc0, a0.z, w2); FMA4(hacc0, a0.w, w3);
            FMA4(hacc1, a1.x, w0); FMA4(hacc1, a1.y, w1);
            FMA4(hacc1, a1.z, w2); FMA4(hacc1, a1.w, w3);
        }
    }
    __syncthreads();

    // ---- p1b: write H ; degrees (spare threads) ----
    if (tid < 160) {
        int np = tid >> 3, fq = tid & 7;
        int n0 = 2 * np, n1 = n0 + 1;
        ((float4*)(sH + n0 * SH))[fq] = hacc0;
        ((float4*)(sH + n1 * SH))[fq] = hacc1;
    } else if (tid < 200) {
        int c = tid - 160; float s = 0.f;
#pragma unroll
        for (int r = 0; r < NPG; r++) s += sA[r * NPG + c];
        sdinv[c] = rsqrtf(s + 1.f);
    } else if (tid < 240) {
        int n = tid - 200; float s = 0.f;
#pragma unroll
        for (int m = 0; m < NPG; m++) s += sA[n * NPG + m];
        srowsA[n] = s;
    }
    __syncthreads();

    // ---- p3: Xd = relu(D^-1/2 (A+I) D^-1/2 H + b1)  [dinv folded] ----
    if (tid < 160) {
        int cp = tid >> 3, fq = tid & 7;
        int c0 = 2 * cp, c1 = c0 + 1;
        float4 acc0 = {0.f,0.f,0.f,0.f}, acc1 = {0.f,0.f,0.f,0.f};
#pragma unroll 8
        for (int r = 0; r < NPG; r++) {
            float2 a2 = *(const float2*)&sA[r * NPG + c0];
            float dv = sdinv[r];
            float4 bv = ((const float4*)(sH + r * SH))[fq];
            FMA4(acc0, a2.x * dv, bv);
            FMA4(acc1, a2.y * dv, bv);
        }
        float4 bb = ((const float4*)b_c1)[fq];
        float4 h0 = ((const float4*)(sH + c0 * SH))[fq];
        float4 h1 = ((const float4*)(sH + c1 * SH))[fq];
        float d0 = sdinv[c0], d1 = sdinv[c1];
        float4 r0, r1;
        r0.x = fmaxf(fmaf(d0, fmaf(d0, h0.x, acc0.x), bb.x), 0.f);
        r0.y = fmaxf(fmaf(d0, fmaf(d0, h0.y, acc0.y), bb.y), 0.f);
        r0.z = fmaxf(fmaf(d0, fmaf(d0, h0.z, acc0.z), bb.z), 0.f);
        r0.w = fmaxf(fmaf(d0, fmaf(d0, h0.w, acc0.w), bb.w), 0.f);
        r1.x = fmaxf(fmaf(d1, fmaf(d1, h1.x, acc1.x), bb.x), 0.f);
        r1.y = fmaxf(fmaf(d1, fmaf(d1, h1.y, acc1.y), bb.y), 0.f);
        r1.z = fmaxf(fmaf(d1, fmaf(d1, h1.z, acc1.z), bb.z), 0.f);
        r1.w = fmaxf(fmaf(d1, fmaf(d1, h1.w, acc1.w), bb.w), 0.f);
        ((float4*)(sXd + c0 * SH))[fq] = r0;
        ((float4*)(sXd + c1 * SH))[fq] = r1;
    }
    __syncthreads();

    // ---- p4: S1 logits = Xd @ Wp1 + bp1  (S1 overwrites dead H) ----
    if (tid < 100) {
        int np = tid / 5, lq = tid - np * 5;
        int n0 = 2 * np, n1 = n0 + 1;
        const float4* wg = (const float4*)w_p1;
        float4 bb = ((const float4*)b_p1)[lq];
        float4 acc0 = bb, acc1 = bb;
#pragma unroll 8
        for (int k = 0; k < HID; k++) {
            float a0 = sXd[n0 * SH + k];
            float a1 = sXd[n1 * SH + k];
            float4 w = wg[k * 5 + lq];
            FMA4(acc0, a0, w); FMA4(acc1, a1, w);
        }
        ((float4*)(sS + n0 * K1))[lq] = acc0;
        ((float4*)(sS + n1 * K1))[lq] = acc1;
    }
    __syncthreads();

    // ---- p5: softmax1 ----
    if (tid < NPG) {
        float* row = sS + tid * K1;
        float v[K1]; float m = -3.0e38f;
#pragma unroll
        for (int k = 0; k < K1; k++) { v[k] = row[k]; m = fmaxf(m, v[k]); }
        float ssum = 0.f;
#pragma unroll
        for (int k = 0; k < K1; k++) { v[k] = __expf(v[k] - m); ssum += v[k]; }
        float inv = 1.f / ssum;
#pragma unroll
        for (int k = 0; k < K1; k++) row[k] = v[k] * inv;
    }
    __syncthreads();

    // ---- p6: AS = A @ S ; SS = S^T S ----
    if (tid < 100) {
        int np = tid / 5, lq = tid - np * 5;
        int n0 = 2 * np, n1 = n0 + 1;
        const float4* sb4 = (const float4*)sS;
        float4 acc0 = {0.f,0.f,0.f,0.f}, acc1 = {0.f,0.f,0.f,0.f};
#pragma unroll
        for (int m4 = 0; m4 < NPG / 4; m4++) {
            float4 a0 = *(const float4*)&sA[n0 * NPG + 4 * m4];
            float4 a1 = *(const float4*)&sA[n1 * NPG + 4 * m4];
            float4 b0 = sb4[(4*m4+0)*5 + lq];
            float4 b1 = sb4[(4*m4+1)*5 + lq];
            float4 b2v = sb4[(4*m4+2)*5 + lq];
            float4 b3v = sb4[(4*m4+3)*5 + lq];
            FMA4(acc0, a0.x, b0); FMA4(acc0, a0.y, b1);
            FMA4(acc0, a0.z, b2v); FMA4(acc0, a0.w, b3v);
            FMA4(acc1, a1.x, b0); FMA4(acc1, a1.y, b1);
            FMA4(acc1, a1.z, b2v); FMA4(acc1, a1.w, b3v);
        }
        ((float4*)(sAS + n0 * K1))[lq] = acc0;
        ((float4*)(sAS + n1 * K1))[lq] = acc1;
    } else if (tid < 150) {
        int oo = tid - 100;
        int kp = oo / 5, lq = oo - kp * 5;
        int k0 = 2 * kp, k1 = k0 + 1;
        float4 acc0 = {0.f,0.f,0.f,0.f}, acc1 = {0.f,0.f,0.f,0.f};
#pragma unroll 8
        for (int n = 0; n < NPG; n++) {
            float2 s2v = *(const float2*)&sS[n * K1 + k0];
            float4 bv = ((const float4*)(sS + n * K1))[lq];
            FMA4(acc0, s2v.x, bv); FMA4(acc1, s2v.y, bv);
        }
        ((float4*)(sSS + k0 * K1))[lq] = acc0;
        ((float4*)(sSS + k1 * K1))[lq] = acc1;
    }
    __syncthreads();

    // ---- p7: A2 = S^T AS (raw) ; X2 = S^T Xd (into sA+400) ; den1 terms ----
    if (tid < 50) {
        int kp = tid / 5, lq = tid - kp * 5;
        int k0 = 2 * kp, k1 = k0 + 1;
        float4 acc0 = {0.f,0.f,0.f,0.f}, acc1 = {0.f,0.f,0.f,0.f};
#pragma unroll 8
        for (int n = 0; n < NPG; n++) {
            float2 s2v = *(const float2*)&sS[n * K1 + k0];
            float4 bv = ((const float4*)(sAS + n * K1))[lq];
            FMA4(acc0, s2v.x, bv); FMA4(acc1, s2v.y, bv);
        }
        ((float4*)(sA2 + k0 * K1))[lq] = acc0;
        ((float4*)(sA2 + k1 * K1))[lq] = acc1;
    } else if (tid < 130) {
        int oo = tid - 50;
        int kp = oo >> 3, fq = oo & 7;
        int k0 = 2 * kp, k1 = k0 + 1;
        float4 acc0 = {0.f,0.f,0.f,0.f}, acc1 = {0.f,0.f,0.f,0.f};
#pragma unroll 8
        for (int n = 0; n < NPG; n++) {
            float2 s2v = *(const float2*)&sS[n * K1 + k0];
            float4 bv = ((const float4*)(sXd + n * SH))[fq];
            FMA4(acc0, s2v.x, bv); FMA4(acc1, s2v.y, bv);
        }
        ((float4*)(sX2 + k0 * SH))[fq] = acc0;
        ((float4*)(sX2 + k1 * SH))[fq] = acc1;
    } else if (tid < 170) {
        int n = tid - 130;
        float s2 = 0.f;
#pragma unroll
        for (int k = 0; k < K1; k++) { float v = sS[n * K1 + k]; s2 = fmaf(v, v, s2); }
        sden[n] = srowsA[n] * s2;
    }
    __syncthreads();

    // ---- p8: stats (3 waves) + XW2r/XW2o strided matmuls ----
    if (wid == 0) {              // closed-form ortho1 from SS
        float f = 0.f, tr = 0.f;
        for (int i = lane; i < K1 * K1; i += 64) {
            float t = sSS[i];
            f = fmaf(t, t, f);
            if (i % (K1 + 1) == 0) tr += t;
        }
        f = wave_red(f); tr = wave_red(tr);
        if (lane == 0)
            sc[2] = sqrtf(fmaxf(2.f - 2.f * tr / (sqrtf(f) * 4.47213595499958f), 0.f));
    } else if (wid == 1) {       // num1 = trace(A2) ; rownorm1 (A2 kept raw)
        float v = 0.f;
        if (lane < K1) {
            float s = 0.f;
#pragma unroll
            for (int l = 0; l < K1; l++) s += sA2[lane * K1 + l];
            float d = sA2[lane * (K1 + 1)];
            srowm[lane] = 1.f / (sqrtf(s - d) + EPSF);
            v = d;
        }
        v = wave_red(v);
        if (lane == 0) sc[0] = v;
    } else if (wid == 2) {       // den1
        float v = (lane < NPG) ? sden[lane] : 0.f;
        v = wave_red(v);
        if (lane == 0) sc[1] = v;
    }
    for (int o = tid; o < 320; o += NT) {
        int first = o < 160; int m = first ? o : o - 160;
        int n = m >> 3, fq = m & 7;
        const float4* wg = (const float4*)(first ? w2r_ : w2o_);
        float4 acc = {0.f,0.f,0.f,0.f};
#pragma unroll 8
        for (int k = 0; k < HID; k++) {
            float a = sX2[n * SH + k];
            FMA4(acc, a, wg[k * 8 + fq]);
        }
        ((float4*)((first ? sXw2r : sXw2o) + n * SH))[fq] = acc;
    }
    __syncthreads();

    // ---- pC: X2' = relu(adj1n @ XW2r + XW2o + b2)  [folded, diag skipped] --
    if (tid < 160) {
        int k = tid >> 3, fq = tid & 7;
        float4 acc = {0.f,0.f,0.f,0.f};
#pragma unroll
        for (int l = 0; l < K1; l++) {
            float a = (l == k) ? 0.f : sA2[k * K1 + l];
            float4 w = ((const float4*)(sXw2r + l * SH))[fq];
            FMA4(acc, a * srowm[l], w);
        }
        float4 bb = ((const float4*)b2_)[fq];
        float4 oo = ((const float4*)(sXw2o + k * SH))[fq];
        float rk = srowm[k];
        float4 r;
        r.x = fmaxf(fmaf(rk, acc.x, oo.x + bb.x), 0.f);
        r.y = fmaxf(fmaf(rk, acc.y, oo.y + bb.y), 0.f);
        r.z = fmaxf(fmaf(rk, acc.z, oo.z + bb.z), 0.f);
        r.w = fmaxf(fmaf(rk, acc.w, oo.w + bb.w), 0.f);
        ((float4*)(sX2 + k * SH))[fq] = r;
    }
    __syncthreads();

    // ---- p11: S2 logits + softmax2 fused (one thread per row) ----
    if (tid < K1) {
        float acc[K2];
#pragma unroll
        for (int q = 0; q < K2; q++) acc[q] = b_p2[q];
#pragma unroll 8
        for (int j = 0; j < HID; j++) {
            float a = sX2[tid * SH + j];
#pragma unroll
            for (int q = 0; q < K2; q++) acc[q] = fmaf(a, w_p2[j * K2 + q], acc[q]);
        }
        float m = -3.0e38f;
#pragma unroll
        for (int q = 0; q < K2; q++) m = fmaxf(m, acc[q]);
        float ssum = 0.f;
#pragma unroll
        for (int q = 0; q < K2; q++) { acc[q] = __expf(acc[q] - m); ssum += acc[q]; }
        float inv = 1.f / ssum;
#pragma unroll
        for (int q = 0; q < K2; q++) sS2[tid * K2 + q] = acc[q] * inv;
    }
    __syncthreads();

    // ---- p12: AS2 = adj1n@S2 ; SS2 ; X3 = S2^T X2' ; den2 terms ----
    for (int o = tid; o < 400; o += NT) {
        if (o < 200) {
            int n = o / K2, l = o - n * K2;
            float acc = 0.f;
#pragma unroll
            for (int m = 0; m < K1; m++) {
                float a = (m == n) ? 0.f : sA2[n * K1 + m];
                acc = fmaf(a * srowm[m], sS2[m * K2 + l], acc);
            }
            sAS2[n * K2 + l] = acc * srowm[n];
        } else if (o < 300) {
            int oo = o - 200; int k = oo / K2, l = oo - k * K2;
            float acc = 0.f;
#pragma unroll
            for (int n = 0; n < K1; n++) acc = fmaf(sS2[n * K2 + k], sS2[n * K2 + l], acc);
            sSS[oo] = acc;
        } else if (o < 380) {
            int oo = o - 300; int k = oo >> 3, fq = oo & 7;
            float4 acc = {0.f,0.f,0.f,0.f};
#pragma unroll
            for (int n = 0; n < K1; n++) {
                float a = sS2[n * K2 + k];
                float4 bv = ((const float4*)(sX2 + n * SH))[fq];
                FMA4(acc, a, bv);
            }
            ((float4*)(sX3 + k * SH))[fq] = acc;
        } else {
            int n = o - 380;
            float da = 0.f, s2 = 0.f;
#pragma unroll
            for (int l = 0; l < K1; l++) {
                float a = (l == n) ? 0.f : sA2[n * K1 + l];
                da = fmaf(a, srowm[l], da);
            }
            da *= srowm[n];
#pragma unroll
            for (int q = 0; q < K2; q++) { float v = sS2[n * K2 + q]; s2 = fmaf(v, v, s2); }
            sden[n] = da * s2;
        }
    }
    __syncthreads();

    // ---- p13: A3 = S2^T AS2 (raw, over dead X2) ; den2 ; ortho2 ----
    if (tid < K2 * K2) {
        int k = tid / K2, l = tid - k * K2;
        float acc = 0.f;
#pragma unroll
        for (int n = 0; n < K1; n++) acc = fmaf(sS2[n * K2 + k], sAS2[n * K2 + l], acc);
        sA3[tid] = acc;
    } else if (wid == 2) {
        float v = (lane < K1) ? sden[lane] : 0.f;
        v = wave_red(v);
        if (lane == 0) sc[5] = v;
    } else if (wid == 3) {
        float f = 0.f, tr = 0.f;
        for (int i = lane; i < K2 * K2; i += 64) {
            float t = sSS[i];
            f = fmaf(t, t, f);
            if (i % (K2 + 1) == 0) tr += t;
        }
        f = wave_red(f); tr = wave_red(tr);
        if (lane == 0)
            sc[6] = sqrtf(fmaxf(2.f - 2.f * tr / (sqrtf(f) * 3.1622776601683795f), 0.f));
    }
    __syncthreads();

    // ---- p14: XW3r/XW3o ; rownorm2 ; loss write ----
    if (tid < 160) {
        bool first = (tid < 80);
        int oo = first ? tid : tid - 80;
        int n = oo >> 3, fq = oo & 7;
        const float4* wg = (const float4*)(first ? w3r_ : w3o_);
        float4 acc = {0.f,0.f,0.f,0.f};
#pragma unroll 8
        for (int k = 0; k < HID; k++) {
            float a = sX3[n * SH + k];
            FMA4(acc, a, wg[k * 8 + fq]);
        }
        if (first) ((float4*)(sW3r + n * SH))[fq] = acc;
        else       ((float4*)(sW3o + n * SH))[fq] = acc;
    } else if (tid >= 160 && tid < 160 + K2) {
        int l = tid - 160;
        float s = 0.f;
#pragma unroll
        for (int m = 0; m < K2; m++) s += sA3[l * K2 + m];
        s -= sA3[l * (K2 + 1)];
        srowm[l] = 1.f / (sqrtf(s) + EPSF);
    } else if (tid == 200) {
        float num2 = 0.f;
#pragma unroll
        for (int k = 0; k < K2; k++) num2 += sA3[k * (K2 + 1)];
        wsg[g] = -(sc[0] / sc[1]) + sc[2] - num2 / sc[5] + sc[6];
    }
    __syncthreads();

    // ---- p15: X4 = adj2n @ XW3r + XW3o + b3  [folded, diag skipped] ----
    if (tid < 80) {
        int k = tid >> 3, fq = tid & 7;
        float4 acc = {0.f,0.f,0.f,0.f};
#pragma unroll
        for (int l = 0; l < K2; l++) {
            float a = (l == k) ? 0.f : sA3[k * K2 + l];
            float4 w = ((const float4*)(sW3r + l * SH))[fq];
            FMA4(acc, a * srowm[l], w);
        }
        float4 bb = ((const float4*)b3_)[fq];
        float4 oo = ((const float4*)(sW3o + k * SH))[fq];
        float rk = srowm[k];
        float4 r;
        r.x = fmaf(rk, acc.x, oo.x + bb.x);
        r.y = fmaf(rk, acc.y, oo.y + bb.y);
        r.z = fmaf(rk, acc.z, oo.z + bb.z);
        r.w = fmaf(rk, acc.w, oo.w + bb.w);
        ((float4*)(sX4 + k * SH))[fq] = r;
    }
    __syncthreads();

    // ---- p16: mean pool + MLP head (wave 0, shuffle-based) ----
    if (wid == 0) {
        int f = lane & 31;
        float pool = 0.f;
#pragma unroll
        for (int n = 0; n < K2; n++) pool += sX4[n * SH + f];
        pool *= (1.f / K2);
        float acc = b_l1[f];
#pragma unroll
        for (int j = 0; j < HID; j++)
            acc = fmaf(__shfl(pool, j, 64), w_l1[j * HID + f], acc);
        float t1 = fmaxf(acc, 0.f);
        int o = (lane < OUTC) ? lane : 0;
        float acc2 = b_l2[o];
#pragma unroll
        for (int j = 0; j < HID; j++)
            acc2 = fmaf(__shfl(t1, j, 64), w_l2[j * OUTC + o], acc2);
        if (lane < OUTC) out[(size_t)g * OUTC + lane] = acc2;
    }
}

__global__ void loss_reduce(const float* __restrict__ wsg, float* __restrict__ out)
{
    __shared__ float sred[4];
    int tid = threadIdx.x;
    float s = 0.f;
    for (int i = tid; i < Bg; i += NT) s += wsg[i];
    s = wave_red(s);
    if ((tid & 63) == 0) sred[tid >> 6] = s;
    __syncthreads();
    if (tid == 0) out[(size_t)Bg * OUTC] = (sred[0] + sred[1] + sred[2] + sred[3]) * (1.f / Bg);
}

extern "C" void kernel_launch(void* const* d_in, const int* in_sizes, int n_in,
                              void* d_out, int out_size, void* d_ws, size_t ws_size,
                              hipStream_t stream)
{
    const float* x    = (const float*)d_in[0];
    const int*   ei   = (const int*)  d_in[1];
    // d_in[2] = batch (unused: graphs are contiguous blocks of NPG nodes)
    const float* w_c1 = (const float*)d_in[3];
    const float* b_c1 = (const float*)d_in[4];
    const float* w_p1 = (const float*)d_in[5];
    const float* b_p1 = (const float*)d_in[6];
    const float* w2r  = (const float*)d_in[7];
    const float* b2   = (const float*)d_in[8];
    const float* w2o  = (const float*)d_in[9];
    const float* w_p2 = (const float*)d_in[10];
    const float* b_p2 = (const float*)d_in[11];
    const float* w3r  = (const float*)d_in[12];
    const float* b3   = (const float*)d_in[13];
    const float* w3o  = (const float*)d_in[14];
    const float* w_l1 = (const float*)d_in[15];
    const float* b_l1 = (const float*)d_in[16];
    const float* w_l2 = (const float*)d_in[17];
    const float* b_l2 = (const float*)d_in[18];
    float* out = (float*)d_out;
    float* wsg = (float*)d_ws;

    hipLaunchKernelGGL(mincut_fused, dim3(Bg), dim3(NT), 0, stream,
                       x, ei, w_c1, b_c1, w_p1, b_p1, w2r, b2, w2o,
                       w_p2, b_p2, w3r, b3, w3o, w_l1, b_l1, w_l2, b_l2,
                       out, wsg);
    hipLaunchKernelGGL(loss_reduce, dim3(1), dim3(NT), 0, stream, wsg, out);
}

// Round 15
// 232.876 us; speedup vs baseline: 1.3524x; 1.0539x over previous
//
#include <hip/hip_runtime.h>

#define NT 256

constexpr int Bg   = 8192;      // graphs
constexpr int NPG  = 40;
constexpr int EPG  = 640;
constexpr int IN_  = 64;
constexpr int HID  = 32;
constexpr int K1   = 20;
constexpr int K2   = 10;
constexpr int OUTC = 10;
constexpr int NE   = Bg * NPG * 16;
constexpr int SH   = 36;        // padded 32-wide row stride
constexpr float EPSF = 1e-15f;

#define FMA4(acc, a, b) do { \
    float _s = (a); \
    acc.x = fmaf(_s, (b).x, acc.x); \
    acc.y = fmaf(_s, (b).y, acc.y); \
    acc.z = fmaf(_s, (b).z, acc.z); \
    acc.w = fmaf(_s, (b).w, acc.w); } while (0)

__device__ __forceinline__ float wave_red(float v) {
#pragma unroll
    for (int off = 32; off > 0; off >>= 1) v += __shfl_down(v, off, 64);
    return v;
}

// LDS overlay identical to r12 (~20.9 KB -> 7 blocks/CU). DS-pipe relief:
// f4/f2 vectorized LDS reads, 4-wide register tiles in p3/p7, diag via
// full-sum+subtract, wave-aligned task partitions.
// BUG FIXED from r13: p6 AS branch used 50 threads with 2-row tiles ->
// AS rows 20-39 never written (stale LDS fed A2). Restored to 100 threads.
// NOTE: __launch_bounds__(256,4) — (256,6) forced 40 VGPR + 38KB spill (r4).
__global__ __launch_bounds__(NT, 4)
void mincut_fused(const float* __restrict__ x, const int* __restrict__ ei,
                  const float* __restrict__ w_c1, const float* __restrict__ b_c1,
                  const float* __restrict__ w_p1, const float* __restrict__ b_p1,
                  const float* __restrict__ w2r_, const float* __restrict__ b2_,
                  const float* __restrict__ w2o_,
                  const float* __restrict__ w_p2, const float* __restrict__ b_p2,
                  const float* __restrict__ w3r_, const float* __restrict__ b3_,
                  const float* __restrict__ w3o_,
                  const float* __restrict__ w_l1, const float* __restrict__ b_l1,
                  const float* __restrict__ w_l2, const float* __restrict__ b_l2,
                  float* __restrict__ out, float* __restrict__ wsg)
{
    __shared__ __align__(16) float sA[NPG * NPG];    // 1600
    __shared__ __align__(16) float sB[2000];
    __shared__ __align__(16) float sXd[NPG * SH];    // 1440
    __shared__ __align__(16) float sdinv[NPG];
    __shared__ __align__(16) float srowsA[NPG];
    __shared__ __align__(16) float srowm[NPG];
    __shared__ __align__(16) float sden[NPG];
    __shared__ __align__(16) float sc[8];
    // sc: [0]num1 [1]den1 [2]o1 [5]den2 [6]o2

    float* sA2  = sA;            // 20x20 raw
    float* sX2  = sA + 400;      // 20xSH  (p7-p12)
    float* sA3  = sA + 400;      // 10x10 raw (p13+, X2 dead)
    float* sH   = sB;            // 40xSH
    float* sS   = sB;            // 40x20
    float* sAS  = sB + 800;      // 40x20
    float* sS2  = sB + 800;      // 20x10
    float* sAS2 = sB + 1000;     // 20x10
    float* sX3  = sB + 1200;     // 10xSH
    float* sX4  = sB + 1200;     // 10xSH (after X3 dead)
    float* sSS  = sB + 1600;     // 400 (SS then SS2)
    float* sXw2r= sXd;           // 20xSH
    float* sXw2o= sXd + 720;     // 20xSH
    float* sW3r = sXd;           // 10xSH
    float* sW3o = sXd + 360;     // 10xSH

    const int g    = blockIdx.x;
    const int tid  = threadIdx.x;
    const int lane = tid & 63;
    const int wid  = tid >> 6;

    // ---- p0: edges -> regs, zero A ----
    int er0, ec0, er1, ec1, er2 = -1, ec2 = 0;
    {
        const int eb = g * EPG, nb = g * NPG;
        int e = eb + tid;
        er0 = ei[e] - nb; ec0 = ei[NE + e] - nb;
        e += NT;
        er1 = ei[e] - nb; ec1 = ei[NE + e] - nb;
        if (tid + 2 * NT < EPG) {
            e += NT;
            er2 = ei[e] - nb; ec2 = ei[NE + e] - nb;
        }
    }
    for (int i = tid; i < NPG * NPG; i += NT) sA[i] = 0.f;
    __syncthreads();

    // ---- p1: adj scatter + H = X @ W1 (X from global, held in registers) ----
    atomicAdd(&sA[er0 * NPG + ec0], 1.f);
    atomicAdd(&sA[er1 * NPG + ec1], 1.f);
    if (er2 >= 0) atomicAdd(&sA[er2 * NPG + ec2], 1.f);

    float4 hacc0 = {0.f,0.f,0.f,0.f}, hacc1 = {0.f,0.f,0.f,0.f};
    if (tid < 160) {
        int np = tid >> 3, fq = tid & 7;
        int n0 = 2 * np, n1 = n0 + 1;
        const float4* x0 = (const float4*)(x + (size_t)g * (NPG * IN_) + n0 * IN_);
        const float4* x1 = (const float4*)(x + (size_t)g * (NPG * IN_) + n1 * IN_);
        const float4* wg = (const float4*)w_c1;
#pragma unroll 4
        for (int kk = 0; kk < IN_ / 4; kk++) {
            float4 a0 = x0[kk], a1 = x1[kk];
            float4 w0 = wg[(4*kk+0)*8 + fq];
            float4 w1 = wg[(4*kk+1)*8 + fq];
            float4 w2 = wg[(4*kk+2)*8 + fq];
            float4 w3 = wg[(4*kk+3)*8 + fq];
            FMA4(hacc0, a0.x, w0); FMA4(hacc0, a0.y, w1);
            FMA4(hacc0, a0.z, w2); FMA4(hacc0, a0.w, w3);
            FMA4(hacc1, a1.x, w0); FMA4(hacc1, a1.y, w1);
            FMA4(hacc1, a1.z, w2); FMA4(hacc1, a1.w, w3);
        }
    }
    __syncthreads();

    // ---- p1b: write H (waves 0-2) ; degrees on wave 3 (f4 reads) ----
    if (tid < 160) {
        int np = tid >> 3, fq = tid & 7;
        int n0 = 2 * np, n1 = n0 + 1;
        ((float4*)(sH + n0 * SH))[fq] = hacc0;
        ((float4*)(sH + n1 * SH))[fq] = hacc1;
    } else if (tid >= 192 && tid < 202) {      // col sums -> dinv (4 cols each)
        int c0 = 4 * (tid - 192);
        float4 s = {0.f,0.f,0.f,0.f};
#pragma unroll 8
        for (int r = 0; r < NPG; r++) {
            float4 a = *(const float4*)&sA[r * NPG + c0];
            s.x += a.x; s.y += a.y; s.z += a.z; s.w += a.w;
        }
        sdinv[c0+0] = rsqrtf(s.x + 1.f);
        sdinv[c0+1] = rsqrtf(s.y + 1.f);
        sdinv[c0+2] = rsqrtf(s.z + 1.f);
        sdinv[c0+3] = rsqrtf(s.w + 1.f);
    } else if (tid >= 202 && tid < 212) {      // row sums (4 rows each)
        int r0 = 4 * (tid - 202);
        float s0 = 0.f, s1 = 0.f, s2 = 0.f, s3 = 0.f;
#pragma unroll
        for (int j = 0; j < 10; j++) {
            float4 a0 = *(const float4*)&sA[(r0+0) * NPG + 4*j];
            float4 a1 = *(const float4*)&sA[(r0+1) * NPG + 4*j];
            float4 a2 = *(const float4*)&sA[(r0+2) * NPG + 4*j];
            float4 a3 = *(const float4*)&sA[(r0+3) * NPG + 4*j];
            s0 += a0.x + a0.y + a0.z + a0.w;
            s1 += a1.x + a1.y + a1.z + a1.w;
            s2 += a2.x + a2.y + a2.z + a2.w;
            s3 += a3.x + a3.y + a3.z + a3.w;
        }
        srowsA[r0+0] = s0; srowsA[r0+1] = s1;
        srowsA[r0+2] = s2; srowsA[r0+3] = s3;
    }
    __syncthreads();

    // ---- p3: Xd = relu(D^-1/2 (A+I) D^-1/2 H + b1)  [4-col tiles, f4 A] ----
    if (tid < 80) {
        int cp = tid >> 3, fq = tid & 7;
        int c0 = 4 * cp;
        float4 acc0 = {0.f,0.f,0.f,0.f}, acc1 = {0.f,0.f,0.f,0.f};
        float4 acc2 = {0.f,0.f,0.f,0.f}, acc3 = {0.f,0.f,0.f,0.f};
#pragma unroll 8
        for (int r = 0; r < NPG; r++) {
            float4 a = *(const float4*)&sA[r * NPG + c0];
            float dv = sdinv[r];
            float4 bv = ((const float4*)(sH + r * SH))[fq];
            FMA4(acc0, a.x * dv, bv);
            FMA4(acc1, a.y * dv, bv);
            FMA4(acc2, a.z * dv, bv);
            FMA4(acc3, a.w * dv, bv);
        }
        float4 bb = ((const float4*)b_c1)[fq];
#pragma unroll
        for (int i = 0; i < 4; i++) {
            float4 acc = (i == 0) ? acc0 : (i == 1) ? acc1 : (i == 2) ? acc2 : acc3;
            int c = c0 + i;
            float d = sdinv[c];
            float4 h = ((const float4*)(sH + c * SH))[fq];
            float4 r;
            r.x = fmaxf(fmaf(d, fmaf(d, h.x, acc.x), bb.x), 0.f);
            r.y = fmaxf(fmaf(d, fmaf(d, h.y, acc.y), bb.y), 0.f);
            r.z = fmaxf(fmaf(d, fmaf(d, h.z, acc.z), bb.z), 0.f);
            r.w = fmaxf(fmaf(d, fmaf(d, h.w, acc.w), bb.w), 0.f);
            ((float4*)(sXd + c * SH))[fq] = r;
        }
    }
    __syncthreads();

    // ---- p4: S1 logits = Xd @ Wp1 + bp1  (f4 Xd reads) ----
    if (tid < 100) {
        int np = tid / 5, lq = tid - np * 5;
        int n0 = 2 * np, n1 = n0 + 1;
        const float4* wg = (const float4*)w_p1;
        float4 bb = ((const float4*)b_p1)[lq];
        float4 acc0 = bb, acc1 = bb;
#pragma unroll
        for (int j = 0; j < 8; j++) {
            float4 a0 = ((const float4*)(sXd + n0 * SH))[j];
            float4 a1 = ((const float4*)(sXd + n1 * SH))[j];
            float4 w0 = wg[(4*j+0) * 5 + lq];
            float4 w1 = wg[(4*j+1) * 5 + lq];
            float4 w2 = wg[(4*j+2) * 5 + lq];
            float4 w3 = wg[(4*j+3) * 5 + lq];
            FMA4(acc0, a0.x, w0); FMA4(acc0, a0.y, w1);
            FMA4(acc0, a0.z, w2); FMA4(acc0, a0.w, w3);
            FMA4(acc1, a1.x, w0); FMA4(acc1, a1.y, w1);
            FMA4(acc1, a1.z, w2); FMA4(acc1, a1.w, w3);
        }
        ((float4*)(sS + n0 * K1))[lq] = acc0;
        ((float4*)(sS + n1 * K1))[lq] = acc1;
    }
    __syncthreads();

    // ---- p5: softmax1 (f4 row I/O) ----
    if (tid < NPG) {
        float4* row4 = (float4*)(sS + tid * K1);
        float4 v[5];
        float m = -3.0e38f;
#pragma unroll
        for (int j = 0; j < 5; j++) {
            v[j] = row4[j];
            m = fmaxf(m, fmaxf(fmaxf(v[j].x, v[j].y), fmaxf(v[j].z, v[j].w)));
        }
        float ssum = 0.f;
#pragma unroll
        for (int j = 0; j < 5; j++) {
            v[j].x = __expf(v[j].x - m); v[j].y = __expf(v[j].y - m);
            v[j].z = __expf(v[j].z - m); v[j].w = __expf(v[j].w - m);
            ssum += v[j].x + v[j].y + v[j].z + v[j].w;
        }
        float inv = 1.f / ssum;
#pragma unroll
        for (int j = 0; j < 5; j++) {
            v[j].x *= inv; v[j].y *= inv; v[j].z *= inv; v[j].w *= inv;
            row4[j] = v[j];
        }
    }
    __syncthreads();

    // ---- p6: AS = A @ S (waves 0-1, ALL 40 rows) ; SS = S^T S (wave 2) ----
    if (tid < 100) {
        int np = tid / 5, lq = tid - np * 5;
        int n0 = 2 * np, n1 = n0 + 1;
        const float4* sb4 = (const float4*)sS;
        float4 acc0 = {0.f,0.f,0.f,0.f}, acc1 = {0.f,0.f,0.f,0.f};
#pragma unroll
        for (int m4 = 0; m4 < NPG / 4; m4++) {
            float4 a0 = *(const float4*)&sA[n0 * NPG + 4 * m4];
            float4 a1 = *(const float4*)&sA[n1 * NPG + 4 * m4];
            float4 b0 = sb4[(4*m4+0)*5 + lq];
            float4 b1 = sb4[(4*m4+1)*5 + lq];
            float4 b2v = sb4[(4*m4+2)*5 + lq];
            float4 b3v = sb4[(4*m4+3)*5 + lq];
            FMA4(acc0, a0.x, b0); FMA4(acc0, a0.y, b1);
            FMA4(acc0, a0.z, b2v); FMA4(acc0, a0.w, b3v);
            FMA4(acc1, a1.x, b0); FMA4(acc1, a1.y, b1);
            FMA4(acc1, a1.z, b2v); FMA4(acc1, a1.w, b3v);
        }
        ((float4*)(sAS + n0 * K1))[lq] = acc0;
        ((float4*)(sAS + n1 * K1))[lq] = acc1;
    } else if (tid >= 128 && tid < 178) {
        int oo = tid - 128;
        int kp = oo / 5, lq = oo - kp * 5;
        int k0 = 2 * kp, k1 = k0 + 1;
        float4 acc0 = {0.f,0.f,0.f,0.f}, acc1 = {0.f,0.f,0.f,0.f};
#pragma unroll 8
        for (int n = 0; n < NPG; n++) {
            float2 s2v = *(const float2*)&sS[n * K1 + k0];
            float4 bv = ((const float4*)(sS + n * K1))[lq];
            FMA4(acc0, s2v.x, bv); FMA4(acc1, s2v.y, bv);
        }
        ((float4*)(sSS + k0 * K1))[lq] = acc0;
        ((float4*)(sSS + k1 * K1))[lq] = acc1;
    }
    __syncthreads();

    // ---- p7: A2 4-k (wave0) ; X2 4-k (wave1) ; den1 (wave2, f4) ----
    if (tid < 25) {
        int kp = tid / 5, lq = tid - kp * 5;
        int k0 = 4 * kp;
        float4 acc0 = {0.f,0.f,0.f,0.f}, acc1 = {0.f,0.f,0.f,0.f};
        float4 acc2 = {0.f,0.f,0.f,0.f}, acc3 = {0.f,0.f,0.f,0.f};
#pragma unroll 8
        for (int n = 0; n < NPG; n++) {
            float4 sv = *(const float4*)&sS[n * K1 + k0];
            float4 bv = ((const float4*)(sAS + n * K1))[lq];
            FMA4(acc0, sv.x, bv); FMA4(acc1, sv.y, bv);
            FMA4(acc2, sv.z, bv); FMA4(acc3, sv.w, bv);
        }
        ((float4*)(sA2 + (k0+0) * K1))[lq] = acc0;
        ((float4*)(sA2 + (k0+1) * K1))[lq] = acc1;
        ((float4*)(sA2 + (k0+2) * K1))[lq] = acc2;
        ((float4*)(sA2 + (k0+3) * K1))[lq] = acc3;
    } else if (tid >= 64 && tid < 104) {
        int oo = tid - 64;
        int kp = oo >> 3, fq = oo & 7;
        int k0 = 4 * kp;
        float4 acc0 = {0.f,0.f,0.f,0.f}, acc1 = {0.f,0.f,0.f,0.f};
        float4 acc2 = {0.f,0.f,0.f,0.f}, acc3 = {0.f,0.f,0.f,0.f};
#pragma unroll 8
        for (int n = 0; n < NPG; n++) {
            float4 sv = *(const float4*)&sS[n * K1 + k0];
            float4 bv = ((const float4*)(sXd + n * SH))[fq];
            FMA4(acc0, sv.x, bv); FMA4(acc1, sv.y, bv);
            FMA4(acc2, sv.z, bv); FMA4(acc3, sv.w, bv);
        }
        ((float4*)(sX2 + (k0+0) * SH))[fq] = acc0;
        ((float4*)(sX2 + (k0+1) * SH))[fq] = acc1;
        ((float4*)(sX2 + (k0+2) * SH))[fq] = acc2;
        ((float4*)(sX2 + (k0+3) * SH))[fq] = acc3;
    } else if (tid >= 128 && tid < 168) {
        int n = tid - 128;
        float s2 = 0.f;
#pragma unroll
        for (int j = 0; j < 5; j++) {
            float4 v = ((const float4*)(sS + n * K1))[j];
            s2 = fmaf(v.x, v.x, s2); s2 = fmaf(v.y, v.y, s2);
            s2 = fmaf(v.z, v.z, s2); s2 = fmaf(v.w, v.w, s2);
        }
        sden[n] = srowsA[n] * s2;
    }
    __syncthreads();

    // ---- p8: stats (waves 0-2) + XW2r/XW2o matmuls (f4 X2 reads) ----
    if (wid == 0) {              // closed-form ortho1 from SS
        float f = 0.f, tr = 0.f;
        for (int i = lane; i < K1 * K1; i += 64) {
            float t = sSS[i];
            f = fmaf(t, t, f);
            if (i % (K1 + 1) == 0) tr += t;
        }
        f = wave_red(f); tr = wave_red(tr);
        if (lane == 0)
            sc[2] = sqrtf(fmaxf(2.f - 2.f * tr / (sqrtf(f) * 4.47213595499958f), 0.f));
    } else if (wid == 1) {       // num1 = trace(A2) ; rownorm1 (A2 kept raw)
        float v = 0.f;
        if (lane < K1) {
            float s = 0.f;
#pragma unroll
            for (int j = 0; j < 5; j++) {
                float4 a = *(const float4*)&sA2[lane * K1 + 4*j];
                s += a.x + a.y + a.z + a.w;
            }
            float d = sA2[lane * (K1 + 1)];
            srowm[lane] = 1.f / (sqrtf(s - d) + EPSF);
            v = d;
        }
        v = wave_red(v);
        if (lane == 0) sc[0] = v;
    } else if (wid == 2) {       // den1
        float v = (lane < NPG) ? sden[lane] : 0.f;
        v = wave_red(v);
        if (lane == 0) sc[1] = v;
    }
    for (int o = tid; o < 320; o += NT) {
        int first = o < 160; int m = first ? o : o - 160;
        int n = m >> 3, fq = m & 7;
        const float4* wg = (const float4*)(first ? w2r_ : w2o_);
        float4 acc = {0.f,0.f,0.f,0.f};
#pragma unroll
        for (int j = 0; j < 8; j++) {
            float4 a = ((const float4*)(sX2 + n * SH))[j];
            float4 w0 = wg[(4*j+0) * 8 + fq];
            float4 w1 = wg[(4*j+1) * 8 + fq];
            float4 w2 = wg[(4*j+2) * 8 + fq];
            float4 w3 = wg[(4*j+3) * 8 + fq];
            FMA4(acc, a.x, w0); FMA4(acc, a.y, w1);
            FMA4(acc, a.z, w2); FMA4(acc, a.w, w3);
        }
        ((float4*)((first ? sXw2r : sXw2o) + n * SH))[fq] = acc;
    }
    __syncthreads();

    // ---- pC: X2' = relu(adj1n @ XW2r + XW2o + b2)  [f4 A2/srowm, diag-sub] --
    if (tid < 160) {
        int k = tid >> 3, fq = tid & 7;
        float4 a[5];
#pragma unroll
        for (int j = 0; j < 5; j++) {
            float4 av = *(const float4*)&sA2[k * K1 + 4*j];
            float4 rm = *(const float4*)&srowm[4*j];
            a[j].x = av.x * rm.x; a[j].y = av.y * rm.y;
            a[j].z = av.z * rm.z; a[j].w = av.w * rm.w;
        }
        float4 acc = {0.f,0.f,0.f,0.f};
#pragma unroll
        for (int j = 0; j < 5; j++) {
            float4 w0 = ((const float4*)(sXw2r + (4*j+0) * SH))[fq];
            float4 w1 = ((const float4*)(sXw2r + (4*j+1) * SH))[fq];
            float4 w2 = ((const float4*)(sXw2r + (4*j+2) * SH))[fq];
            float4 w3 = ((const float4*)(sXw2r + (4*j+3) * SH))[fq];
            FMA4(acc, a[j].x, w0); FMA4(acc, a[j].y, w1);
            FMA4(acc, a[j].z, w2); FMA4(acc, a[j].w, w3);
        }
        float adiag = sA2[k * (K1 + 1)] * srowm[k];
        float4 wk = ((const float4*)(sXw2r + k * SH))[fq];
        acc.x -= adiag * wk.x; acc.y -= adiag * wk.y;
        acc.z -= adiag * wk.z; acc.w -= adiag * wk.w;
        float4 bb = ((const float4*)b2_)[fq];
        float4 oo = ((const float4*)(sXw2o + k * SH))[fq];
        float rk = srowm[k];
        float4 r;
        r.x = fmaxf(fmaf(rk, acc.x, oo.x + bb.x), 0.f);
        r.y = fmaxf(fmaf(rk, acc.y, oo.y + bb.y), 0.f);
        r.z = fmaxf(fmaf(rk, acc.z, oo.z + bb.z), 0.f);
        r.w = fmaxf(fmaf(rk, acc.w, oo.w + bb.w), 0.f);
        ((float4*)(sX2 + k * SH))[fq] = r;
    }
    __syncthreads();

    // ---- p11: S2 logits + softmax2 fused (f4 reads, f2 writes) ----
    if (tid < K1) {
        float acc[K2];
#pragma unroll
        for (int q = 0; q < K2; q++) acc[q] = b_p2[q];
#pragma unroll
        for (int j = 0; j < 8; j++) {
            float4 a = ((const float4*)(sX2 + tid * SH))[j];
#pragma unroll
            for (int q = 0; q < K2; q++) acc[q] = fmaf(a.x, w_p2[(4*j+0) * K2 + q], acc[q]);
#pragma unroll
            for (int q = 0; q < K2; q++) acc[q] = fmaf(a.y, w_p2[(4*j+1) * K2 + q], acc[q]);
#pragma unroll
            for (int q = 0; q < K2; q++) acc[q] = fmaf(a.z, w_p2[(4*j+2) * K2 + q], acc[q]);
#pragma unroll
            for (int q = 0; q < K2; q++) acc[q] = fmaf(a.w, w_p2[(4*j+3) * K2 + q], acc[q]);
        }
        float m = -3.0e38f;
#pragma unroll
        for (int q = 0; q < K2; q++) m = fmaxf(m, acc[q]);
        float ssum = 0.f;
#pragma unroll
        for (int q = 0; q < K2; q++) { acc[q] = __expf(acc[q] - m); ssum += acc[q]; }
        float inv = 1.f / ssum;
#pragma unroll
        for (int q2 = 0; q2 < 5; q2++) {
            float2 wv; wv.x = acc[2*q2] * inv; wv.y = acc[2*q2+1] * inv;
            *(float2*)&sS2[tid * K2 + 2*q2] = wv;
        }
    }
    __syncthreads();

    // ---- p12: AS2 (waves 0-1) ; SS2+den2 (wave 2) ; X3 (wave 3) ----
    if (tid < 100) {             // AS2: (n, l-pair), f4 A2/srowm + f2 S2
        int n = tid / 5, lp = tid - (tid / 5) * 5;
        int l0 = 2 * lp;
        float accx = 0.f, accy = 0.f;
#pragma unroll
        for (int j = 0; j < 5; j++) {
            float4 av = *(const float4*)&sA2[n * K1 + 4*j];
            float4 rm = *(const float4*)&srowm[4*j];
            float2 s0 = *(const float2*)&sS2[(4*j+0) * K2 + l0];
            float2 s1 = *(const float2*)&sS2[(4*j+1) * K2 + l0];
            float2 s2v = *(const float2*)&sS2[(4*j+2) * K2 + l0];
            float2 s3 = *(const float2*)&sS2[(4*j+3) * K2 + l0];
            float c0 = av.x * rm.x, c1 = av.y * rm.y, c2 = av.z * rm.z, c3 = av.w * rm.w;
            accx = fmaf(c0, s0.x, accx); accy = fmaf(c0, s0.y, accy);
            accx = fmaf(c1, s1.x, accx); accy = fmaf(c1, s1.y, accy);
            accx = fmaf(c2, s2v.x, accx); accy = fmaf(c2, s2v.y, accy);
            accx = fmaf(c3, s3.x, accx); accy = fmaf(c3, s3.y, accy);
        }
        float cd = sA2[n * (K1 + 1)] * srowm[n];
        float2 sn = *(const float2*)&sS2[n * K2 + l0];
        accx -= cd * sn.x; accy -= cd * sn.y;
        float rn = srowm[n];
        float2 wv; wv.x = accx * rn; wv.y = accy * rn;
        *(float2*)&sAS2[n * K2 + l0] = wv;
    } else if (tid >= 128 && tid < 153) {   // SS2: (k-pair, l-pair)
        int oo = tid - 128;
        int kp = oo / 5, lp = oo - kp * 5;
        int k0 = 2 * kp, l0 = 2 * lp;
        float a00 = 0.f, a01 = 0.f, a10 = 0.f, a11 = 0.f;
#pragma unroll
        for (int n = 0; n < K1; n++) {
            float2 a = *(const float2*)&sS2[n * K2 + k0];
            float2 b = *(const float2*)&sS2[n * K2 + l0];
            a00 = fmaf(a.x, b.x, a00); a01 = fmaf(a.x, b.y, a01);
            a10 = fmaf(a.y, b.x, a10); a11 = fmaf(a.y, b.y, a11);
        }
        sSS[(k0+0) * K2 + l0]     = a00;
        sSS[(k0+0) * K2 + l0 + 1] = a01;
        sSS[(k0+1) * K2 + l0]     = a10;
        sSS[(k0+1) * K2 + l0 + 1] = a11;
    } else if (tid >= 160 && tid < 180) {   // den2 terms
        int n = tid - 160;
        float da = 0.f;
#pragma unroll
        for (int j = 0; j < 5; j++) {
            float4 av = *(const float4*)&sA2[n * K1 + 4*j];
            float4 rm = *(const float4*)&srowm[4*j];
            da = fmaf(av.x, rm.x, da); da = fmaf(av.y, rm.y, da);
            da = fmaf(av.z, rm.z, da); da = fmaf(av.w, rm.w, da);
        }
        da -= sA2[n * (K1 + 1)] * srowm[n];
        da *= srowm[n];
        float s2 = 0.f;
#pragma unroll
        for (int q2 = 0; q2 < 5; q2++) {
            float2 v = *(const float2*)&sS2[n * K2 + 2*q2];
            s2 = fmaf(v.x, v.x, s2); s2 = fmaf(v.y, v.y, s2);
        }
        sden[n] = da * s2;
    } else if (tid >= 192 && tid < 232) {   // X3 = S2^T X2' (2-k tiles)
        int oo = tid - 192;
        int kp = oo >> 3, fq = oo & 7;
        int k0 = 2 * kp;
        float4 acc0 = {0.f,0.f,0.f,0.f}, acc1 = {0.f,0.f,0.f,0.f};
#pragma unroll
        for (int n = 0; n < K1; n++) {
            float2 sv = *(const float2*)&sS2[n * K2 + k0];
            float4 bv = ((const float4*)(sX2 + n * SH))[fq];
            FMA4(acc0, sv.x, bv); FMA4(acc1, sv.y, bv);
        }
        ((float4*)(sX3 + (k0+0) * SH))[fq] = acc0;
        ((float4*)(sX3 + (k0+1) * SH))[fq] = acc1;
    }
    __syncthreads();

    // ---- p13: A3 = S2^T AS2 f2-tiled (wave0) ; den2 (w2) ; ortho2 (w3) ----
    if (tid < 25) {
        int kp = tid / 5, lp = tid - kp * 5;
        int k0 = 2 * kp, l0 = 2 * lp;
        float a00 = 0.f, a01 = 0.f, a10 = 0.f, a11 = 0.f;
#pragma unroll
        for (int n = 0; n < K1; n++) {
            float2 sv = *(const float2*)&sS2[n * K2 + k0];
            float2 av = *(const float2*)&sAS2[n * K2 + l0];
            a00 = fmaf(sv.x, av.x, a00); a01 = fmaf(sv.x, av.y, a01);
            a10 = fmaf(sv.y, av.x, a10); a11 = fmaf(sv.y, av.y, a11);
        }
        sA3[(k0+0) * K2 + l0]     = a00;
        sA3[(k0+0) * K2 + l0 + 1] = a01;
        sA3[(k0+1) * K2 + l0]     = a10;
        sA3[(k0+1) * K2 + l0 + 1] = a11;
    } else if (wid == 2) {
        float v = (lane < K1) ? sden[lane] : 0.f;
        v = wave_red(v);
        if (lane == 0) sc[5] = v;
    } else if (wid == 3) {
        float f = 0.f, tr = 0.f;
        for (int i = lane; i < K2 * K2; i += 64) {
            float t = sSS[i];
            f = fmaf(t, t, f);
            if (i % (K2 + 1) == 0) tr += t;
        }
        f = wave_red(f); tr = wave_red(tr);
        if (lane == 0)
            sc[6] = sqrtf(fmaxf(2.f - 2.f * tr / (sqrtf(f) * 3.1622776601683795f), 0.f));
    }
    __syncthreads();

    // ---- p14: XW3r/XW3o (f4 X3 reads) ; rownorm2 + loss (wave 3) ----
    if (tid < 160) {
        bool first = (tid < 80);
        int oo = first ? tid : tid - 80;
        int n = oo >> 3, fq = oo & 7;
        const float4* wg = (const float4*)(first ? w3r_ : w3o_);
        float4 acc = {0.f,0.f,0.f,0.f};
#pragma unroll
        for (int j = 0; j < 8; j++) {
            float4 a = ((const float4*)(sX3 + n * SH))[j];
            float4 w0 = wg[(4*j+0) * 8 + fq];
            float4 w1 = wg[(4*j+1) * 8 + fq];
            float4 w2 = wg[(4*j+2) * 8 + fq];
            float4 w3 = wg[(4*j+3) * 8 + fq];
            FMA4(acc, a.x, w0); FMA4(acc, a.y, w1);
            FMA4(acc, a.z, w2); FMA4(acc, a.w, w3);
        }
        if (first) ((float4*)(sW3r + n * SH))[fq] = acc;
        else       ((float4*)(sW3o + n * SH))[fq] = acc;
    } else if (tid >= 192 && tid < 202) {
        int l = tid - 192;
        float s = 0.f;
#pragma unroll
        for (int j = 0; j < 5; j++) {
            float2 a = *(const float2*)&sA3[l * K2 + 2*j];
            s += a.x + a.y;
        }
        s -= sA3[l * (K2 + 1)];
        srowm[l] = 1.f / (sqrtf(s) + EPSF);
    } else if (tid == 202) {
        float num2 = 0.f;
#pragma unroll
        for (int k = 0; k < K2; k++) num2 += sA3[k * (K2 + 1)];
        wsg[g] = -(sc[0] / sc[1]) + sc[2] - num2 / sc[5] + sc[6];
    }
    __syncthreads();

    // ---- p15: X4 = adj2n @ XW3r + XW3o + b3  [f2 A3/srowm, diag-sub] ----
    if (tid < 80) {
        int k = tid >> 3, fq = tid & 7;
        float4 acc = {0.f,0.f,0.f,0.f};
#pragma unroll
        for (int j = 0; j < 5; j++) {
            float2 av = *(const float2*)&sA3[k * K2 + 2*j];
            float2 rm = *(const float2*)&srowm[2*j];
            float c0 = av.x * rm.x, c1 = av.y * rm.y;
            float4 w0 = ((const float4*)(sW3r + (2*j+0) * SH))[fq];
            float4 w1 = ((const float4*)(sW3r + (2*j+1) * SH))[fq];
            FMA4(acc, c0, w0); FMA4(acc, c1, w1);
        }
        float adiag = sA3[k * (K2 + 1)] * srowm[k];
        float4 wk = ((const float4*)(sW3r + k * SH))[fq];
        acc.x -= adiag * wk.x; acc.y -= adiag * wk.y;
        acc.z -= adiag * wk.z; acc.w -= adiag * wk.w;
        float4 bb = ((const float4*)b3_)[fq];
        float4 oo = ((const float4*)(sW3o + k * SH))[fq];
        float rk = srowm[k];
        float4 r;
        r.x = fmaf(rk, acc.x, oo.x + bb.x);
        r.y = fmaf(rk, acc.y, oo.y + bb.y);
        r.z = fmaf(rk, acc.z, oo.z + bb.z);
        r.w = fmaf(rk, acc.w, oo.w + bb.w);
        ((float4*)(sX4 + k * SH))[fq] = r;
    }
    __syncthreads();

    // ---- p16: mean pool + MLP head (wave 0, shuffle-based) ----
    if (wid == 0) {
        int f = lane & 31;
        float pool = 0.f;
#pragma unroll
        for (int n = 0; n < K2; n++) pool += sX4[n * SH + f];
        pool *= (1.f / K2);
        float acc = b_l1[f];
#pragma unroll
        for (int j = 0; j < HID; j++)
            acc = fmaf(__shfl(pool, j, 64), w_l1[j * HID + f], acc);
        float t1 = fmaxf(acc, 0.f);
        int o = (lane < OUTC) ? lane : 0;
        float acc2 = b_l2[o];
#pragma unroll
        for (int j = 0; j < HID; j++)
            acc2 = fmaf(__shfl(t1, j, 64), w_l2[j * OUTC + o], acc2);
        if (lane < OUTC) out[(size_t)g * OUTC + lane] = acc2;
    }
}

__global__ void loss_reduce(const float* __restrict__ wsg, float* __restrict__ out)
{
    __shared__ float sred[4];
    int tid = threadIdx.x;
    float s = 0.f;
    for (int i = tid; i < Bg; i += NT) s += wsg[i];
    s = wave_red(s);
    if ((tid & 63) == 0) sred[tid >> 6] = s;
    __syncthreads();
    if (tid == 0) out[(size_t)Bg * OUTC] = (sred[0] + sred[1] + sred[2] + sred[3]) * (1.f / Bg);
}

extern "C" void kernel_launch(void* const* d_in, const int* in_sizes, int n_in,
                              void* d_out, int out_size, void* d_ws, size_t ws_size,
                              hipStream_t stream)
{
    const float* x    = (const float*)d_in[0];
    const int*   ei   = (const int*)  d_in[1];
    // d_in[2] = batch (unused: graphs are contiguous blocks of NPG nodes)
    const float* w_c1 = (const float*)d_in[3];
    const float* b_c1 = (const float*)d_in[4];
    const float* w_p1 = (const float*)d_in[5];
    const float* b_p1 = (const float*)d_in[6];
    const float* w2r  = (const float*)d_in[7];
    const float* b2   = (const float*)d_in[8];
    const float* w2o  = (const float*)d_in[9];
    const float* w_p2 = (const float*)d_in[10];
    const float* b_p2 = (const float*)d_in[11];
    const float* w3r  = (const float*)d_in[12];
    const float* b3   = (const float*)d_in[13];
    const float* w3o  = (const float*)d_in[14];
    const float* w_l1 = (const float*)d_in[15];
    const float* b_l1 = (const float*)d_in[16];
    const float* w_l2 = (const float*)d_in[17];
    const float* b_l2 = (const float*)d_in[18];
    float* out = (float*)d_out;
    float* wsg = (float*)d_ws;

    hipLaunchKernelGGL(mincut_fused, dim3(Bg), dim3(NT), 0, stream,
                       x, ei, w_c1, b_c1, w_p1, b_p1, w2r, b2, w2o,
                       w_p2, b_p2, w3r, b3, w3o, w_l1, b_l1, w_l2, b_l2,
                       out, wsg);
    hipLaunchKernelGGL(loss_reduce, dim3(1), dim3(NT), 0, stream, wsg, out);
}